// Round 20
// baseline (195.116 us; speedup 1.0000x reference)
//
#include <hip/hip_runtime.h>
#include <stdint.h>

typedef unsigned short u16;
typedef __attribute__((ext_vector_type(8))) short bf16x8;
typedef __attribute__((ext_vector_type(4))) float f32x4;
typedef __attribute__((ext_vector_type(4))) unsigned int u32x4;
typedef __attribute__((ext_vector_type(2))) unsigned int u32x2;
typedef __attribute__((ext_vector_type(4))) unsigned short u16x4;

#define MFMA16(a, b, c) __builtin_amdgcn_mfma_f32_16x16x32_bf16(a, b, c, 0, 0, 0)
#define VMCNT(N) asm volatile("s_waitcnt vmcnt(" #N ")" ::: "memory")
#define LGKM0() asm volatile("s_waitcnt lgkmcnt(0)" ::: "memory")

__device__ __forceinline__ u16 f2bf(float f) {
  union { float f; uint32_t u; } v; v.f = f;
  uint32_t r = v.u + 0x7FFFu + ((v.u >> 16) & 1u);
  return (u16)(r >> 16);
}

__device__ __forceinline__ float bf2f(u16 u) {
  union { uint32_t u; float f; } v; v.u = ((uint32_t)u) << 16;
  return v.f;
}

__device__ __forceinline__ uint32_t cvt_pk_bf16(float a, float b) {
  uint32_t r;
  asm("v_cvt_pk_bf16_f32 %0, %1, %2" : "=v"(r) : "v"(a), "v"(b));
  return r;
}

// async global->LDS, 16B per lane. LDS dest is wave-uniform base + lane*16.
__device__ __forceinline__ void gload_lds16(const u16* g, u16* l) {
  __builtin_amdgcn_global_load_lds((const __attribute__((address_space(1))) void*)(g),
                                   (__attribute__((address_space(3))) void*)(l), 16, 0, 0);
}

// ------------- prep mega-kernel: LN1 + all weight transposes, one launch -------------
__global__ __launch_bounds__(256) void prep_kernel(
    const float* __restrict__ x, const float* __restrict__ g1,
    const float* __restrict__ be1, u16* __restrict__ h,
    const float* __restrict__ Wq, const float* __restrict__ Wk,
    const float* __restrict__ Wv, u16* __restrict__ BtQKV,
    const float* __restrict__ Wo, u16* __restrict__ WoT,
    const float* __restrict__ W1, u16* __restrict__ W1T,
    const float* __restrict__ W2, u16* __restrict__ W2T) {
  __shared__ float ld[64 * 65];
  __shared__ float red[8];
  int bid = blockIdx.x, tid = threadIdx.x;
  if (bid < 4096) {
    int row = bid;
    float4 v = ((const float4*)(x + (size_t)row * 1024))[tid];
    float s = v.x + v.y + v.z + v.w;
    float ss = v.x * v.x + v.y * v.y + v.z * v.z + v.w * v.w;
#pragma unroll
    for (int m = 1; m < 64; m <<= 1) { s += __shfl_xor(s, m); ss += __shfl_xor(ss, m); }
    int wave = tid >> 6, lane = tid & 63;
    if (lane == 0) { red[wave] = s; red[4 + wave] = ss; }
    __syncthreads();
    s = red[0] + red[1] + red[2] + red[3];
    ss = red[4] + red[5] + red[6] + red[7];
    float mean = s * (1.0f / 1024.0f);
    float var = ss * (1.0f / 1024.0f) - mean * mean;
    float rstd = rsqrtf(var + 1e-5f);
    float4 gv = ((const float4*)g1)[tid];
    float4 bv = ((const float4*)be1)[tid];
    u16x4 o;
    o.x = f2bf((v.x - mean) * rstd * gv.x + bv.x);
    o.y = f2bf((v.y - mean) * rstd * gv.y + bv.y);
    o.z = f2bf((v.z - mean) * rstd * gv.z + bv.z);
    o.w = f2bf((v.w - mean) * rstd * gv.w + bv.w);
    *(u16x4*)(h + (size_t)row * 1024 + tid * 4) = o;
    return;
  }
  int bid2 = bid - 4096;
  const float* I;
  u16* O;
  int K, N, n0, k0;
  if (bid2 < 768) {        // QKV heads: 48 heads x 16 k-tiles
    int hb = bid2 >> 4, kt = bid2 & 15;
    int ww = hb >> 4, head = hb & 15;
    I = ((ww == 0) ? Wq : (ww == 1) ? Wk : Wv) + (size_t)head * 65536;
    O = BtQKV + (size_t)ww * 1048576 + (size_t)head * 65536;
    K = 1024; N = 64; k0 = kt * 64; n0 = 0;
  } else if (bid2 < 1024) {  // Wo: 16k x 16n tiles
    int i2 = bid2 - 768;
    I = Wo; O = WoT; K = 1024; N = 1024;
    k0 = (i2 >> 4) * 64; n0 = (i2 & 15) * 64;
  } else if (bid2 < 2048) {  // W1: 16k x 64n tiles
    int i3 = bid2 - 1024;
    I = W1; O = W1T; K = 1024; N = 4096;
    k0 = (i3 >> 6) * 64; n0 = (i3 & 63) * 64;
  } else {                   // W2: 64k x 16n tiles
    int i4 = bid2 - 2048;
    I = W2; O = W2T; K = 4096; N = 1024;
    k0 = (i4 >> 4) * 64; n0 = (i4 & 15) * 64;
  }
  // load: float4 along n, store LDS [k][n] (2-way bank alias: free)
  int nn4 = tid & 15;        // n = nn4*4
#pragma unroll
  for (int it = 0; it < 4; it++) {
    int kk = (tid >> 4) + it * 16;
    float4 v = *(const float4*)(I + (size_t)(k0 + kk) * N + n0 + nn4 * 4);
    float* dst = ld + kk * 65 + nn4 * 4;
    dst[0] = v.x; dst[1] = v.y; dst[2] = v.z; dst[3] = v.w;
  }
  __syncthreads();
  // write: u16x4 along k (lanes 0-15 cover 128B of one out row; 2-way LDS alias)
  int kc = tid & 15;         // k = kc*4
#pragma unroll
  for (int it = 0; it < 4; it++) {
    int n = (tid >> 4) + it * 16;
    u16x4 w;
    w.x = f2bf(ld[(kc * 4 + 0) * 65 + n]);
    w.y = f2bf(ld[(kc * 4 + 1) * 65 + n]);
    w.z = f2bf(ld[(kc * 4 + 2) * 65 + n]);
    w.w = f2bf(ld[(kc * 4 + 3) * 65 + n]);
    *(u16x4*)(O + (size_t)(n0 + n) * K + k0 + kc * 4) = w;
  }
}

// ------- LayerNorm over bf16 input: x1b bf16 [rows][1024] -> h2 bf16 -------
__global__ __launch_bounds__(256) void ln_bf16_kernel(const u16* __restrict__ xb,
                                                      const float* __restrict__ g,
                                                      const float* __restrict__ beta,
                                                      u16* __restrict__ out) {
  int row = blockIdx.x;
  int tid = threadIdx.x;
  u16x4 vr = *(const u16x4*)(xb + (size_t)row * 1024 + tid * 4);
  float v0 = bf2f(vr.x), v1 = bf2f(vr.y), v2 = bf2f(vr.z), v3 = bf2f(vr.w);
  float s = v0 + v1 + v2 + v3;
  float ss = v0 * v0 + v1 * v1 + v2 * v2 + v3 * v3;
#pragma unroll
  for (int m = 1; m < 64; m <<= 1) { s += __shfl_xor(s, m); ss += __shfl_xor(ss, m); }
  __shared__ float red[8];
  int wave = tid >> 6, lane = tid & 63;
  if (lane == 0) { red[wave] = s; red[4 + wave] = ss; }
  __syncthreads();
  s = red[0] + red[1] + red[2] + red[3];
  ss = red[4] + red[5] + red[6] + red[7];
  float mean = s * (1.0f / 1024.0f);
  float var = ss * (1.0f / 1024.0f) - mean * mean;
  float rstd = rsqrtf(var + 1e-5f);
  float4 gv = ((const float4*)g)[tid];
  float4 bv = ((const float4*)beta)[tid];
  u16x4 o;
  o.x = f2bf((v0 - mean) * rstd * gv.x + bv.x);
  o.y = f2bf((v1 - mean) * rstd * gv.y + bv.y);
  o.z = f2bf((v2 - mean) * rstd * gv.z + bv.z);
  o.w = f2bf((v3 - mean) * rstd * gv.w + bv.w);
  *(u16x4*)(out + (size_t)row * 1024 + tid * 4) = o;
}

// ---------------- 256x256 8-phase GEMM: C[M][N] = A[M][K] * Bt[N][K]^T ----------------
// m201-conformant schedule (r13 proven).
// EP 0: TRANSPOSED QKV scatter — A=BtQKV (features), B=h (tokens):
//       C[feature][token]; thread owns 4 consecutive e within one head ->
//       q/k are packed u16x4 stores; vT scalar. sec = bm0>>10 (block-uniform).
// EP 2: relu+bias bf16 (FFN1).
template <int EP>
__global__ __launch_bounds__(512, 2) void gemm8p(const u16* __restrict__ A,
                                                 const u16* __restrict__ Bt,
                                                 int M, int N, int K, int KS,
                                                 void* __restrict__ out0,
                                                 u16* __restrict__ out1,
                                                 u16* __restrict__ out2,
                                                 const float* __restrict__ bias) {
  __shared__ __align__(16) u16 lds[65536];  // A at 0, B at 32768 (u16 units)
  const int tid = threadIdx.x;
  const int lane = tid & 63, wave = tid >> 6;
  const int lo = lane & 15, hi = lane >> 4;
  const int wm = wave >> 2, wn = wave & 3;
  // XCD swizzle
  int gx = gridDim.x;
  int lin = blockIdx.y * gx + blockIdx.x;
  int nwg = gx * gridDim.y;
  int cpx = nwg >> 3;
  int swz = (lin & 7) * cpx + (lin >> 3);
  int bm0 = (swz / gx) * 256, bn0 = (swz % gx) * 256;
  int kbeg = blockIdx.z * KS;
  int T = KS >> 6;

  int rs_ = tid >> 3, ss_ = (tid & 7) ^ (rs_ & 7);
  const u16* srcA = A + (size_t)(bm0 + rs_) * K + kbeg + ss_ * 8;
  const u16* srcB = Bt + (size_t)(bn0 + rs_) * K + kbeg + ss_ * 8;
  const size_t i1 = (size_t)64 * K;
  const size_t h1 = (size_t)128 * K;
  const int dst0 = wave * 512;
  const int dst1 = 4096 + wave * 512;

  const int rpA = wm * 16 + lo;
  const int rpB = wn * 16 + lo;
  const int sp0 = (hi ^ (lo & 7)) * 8;

  f32x4 acc[8][4] = {};
  bf16x8 a[4][2], b0[2][2], b1[2][2];

  auto stageA = [&](int buf, int h, int koff) {
    const u16* s = srcA + koff + (h ? h1 : 0);
    u16* d = lds + (buf * 2 + h) * 8192;
    gload_lds16(s, d + dst0);
    gload_lds16(s + i1, d + dst1);
  };
  auto stageB = [&](int buf, int h, int koff) {
    const u16* s = srcB + koff + (h ? h1 : 0);
    u16* d = lds + 32768 + (buf * 2 + h) * 8192;
    gload_lds16(s, d + dst0);
    gload_lds16(s + i1, d + dst1);
  };
  auto loadA = [&](int buf, int h) {
    const u16* base = lds + (buf * 2 + h) * 8192 + rpA * 64;
#pragma unroll
    for (int m = 0; m < 4; m++) {
      a[m][0] = *(const bf16x8*)(base + m * 2048 + sp0);
      a[m][1] = *(const bf16x8*)(base + m * 2048 + (sp0 ^ 32));
    }
  };
  auto loadB = [&](bf16x8 (&bb)[2][2], int buf, int g) {
    const u16* base = lds + 32768 + (buf * 2 + g) * 8192 + rpB * 64;
#pragma unroll
    for (int n = 0; n < 2; n++) {
      bb[n][0] = *(const bf16x8*)(base + n * 4096 + sp0);
      bb[n][1] = *(const bf16x8*)(base + n * 4096 + (sp0 ^ 32));
    }
  };
  auto mmac = [&](int mh, int np, bf16x8 (&bb)[2][2]) {
    __builtin_amdgcn_s_setprio(1);
#pragma unroll
    for (int m = 0; m < 4; m++)
#pragma unroll
      for (int n = 0; n < 2; n++) {
        acc[mh + m][np + n] = MFMA16(a[m][0], bb[n][0], acc[mh + m][np + n]);
        acc[mh + m][np + n] = MFMA16(a[m][1], bb[n][1], acc[mh + m][np + n]);
      }
    __builtin_amdgcn_s_setprio(0);
  };

  stageA(0, 0, 0); stageB(0, 0, 0); stageB(0, 1, 0); stageA(0, 1, 0);
  VMCNT(4);
  __builtin_amdgcn_s_barrier();

  for (int t = 0; t < T; ++t) {
    int cur = t & 1, nxt = cur ^ 1;
    bool more = (t + 1 < T);
    int koff = (t + 1) * 64;
    // P1
    loadA(cur, 0); loadB(b0, cur, 0);
    if (more) stageA(nxt, 0, koff);
    __builtin_amdgcn_s_barrier();
    LGKM0();
    __builtin_amdgcn_sched_barrier(0);
    mmac(0, 0, b0);
    __builtin_amdgcn_s_barrier();
    // P2
    loadB(b1, cur, 1);
    if (more) { stageB(nxt, 0, koff); VMCNT(6); } else { VMCNT(2); }
    __builtin_amdgcn_s_barrier();
    LGKM0();
    __builtin_amdgcn_sched_barrier(0);
    mmac(0, 2, b1);
    __builtin_amdgcn_s_barrier();
    // P3
    loadA(cur, 1);
    if (more) { stageB(nxt, 1, koff); VMCNT(6); } else { VMCNT(0); }
    __builtin_amdgcn_s_barrier();
    LGKM0();
    __builtin_amdgcn_sched_barrier(0);
    mmac(4, 0, b0);
    __builtin_amdgcn_s_barrier();
    // P4
    if (more) { stageA(nxt, 1, koff); VMCNT(4); }
    __builtin_amdgcn_s_barrier();
    mmac(4, 2, b1);
    __builtin_amdgcn_s_barrier();
  }

  const int sec = (EP == 0) ? (bm0 >> 10) : 0;  // feature-section, block-uniform
#pragma unroll
  for (int mt = 0; mt < 8; mt++) {
    int gr0 = bm0 + (mt >> 2) * 128 + (mt & 3) * 32 + wm * 16 + hi * 4;
#pragma unroll
    for (int nt = 0; nt < 4; nt++) {
      int gc = bn0 + (nt >> 1) * 128 + (nt & 1) * 64 + wn * 16 + lo;
      if constexpr (EP == 0) {
        // gr = feature (w*1024 + head*64 + e), gc = token (b*2048 + t)
        int b_ = gc >> 11, t_ = gc & 2047;
        int nn = gr0 & 1023, h_ = nn >> 6, e_ = nn & 63;
        size_t bh = (size_t)(b_ * 16 + h_);
        if (sec == 2) {  // vT [bh][e][t]: 4 e-rows, scalar stores
#pragma unroll
          for (int j = 0; j < 4; j++)
            out2[(bh * 64 + e_ + j) * 2048 + t_] = f2bf(acc[mt][nt][j]);
        } else {         // q/k [bh][t][e]: 4 consecutive e -> packed u16x4
          float sc = (sec == 0) ? 0.0450842200f : 1.0f;  // q pre-scale D^-0.5*log2e
          u16* dst = (sec == 0) ? (u16*)out0 : out1;
          u16x4 w;
          w.x = f2bf(acc[mt][nt][0] * sc);
          w.y = f2bf(acc[mt][nt][1] * sc);
          w.z = f2bf(acc[mt][nt][2] * sc);
          w.w = f2bf(acc[mt][nt][3] * sc);
          *(u16x4*)(dst + (bh * 2048 + t_) * 64 + e_) = w;
        }
      } else if constexpr (EP == 2) {
#pragma unroll
        for (int j = 0; j < 4; j++) {
          int gr = gr0 + j;
          float v = acc[mt][nt][j] + bias[gc];
          ((u16*)out0)[(size_t)gr * N + gc] = f2bf(fmaxf(v, 0.0f));
        }
      }
    }
  }
}

// ---- 128x128 8-wave 4-phase GEMM (BK=128), r13 proven schedule ----
// EPR 0 (Wo):   x1b(bf16) = acc + bias + resf(fp32)
// EPR 1 (FFN2): outf(fp32) = acc + bias + bf2f(resb)
template <int EPR>
__global__ __launch_bounds__(512, 2) void gemm128(const u16* __restrict__ A,
                                                  const u16* __restrict__ Bt,
                                                  int M, int N, int K,
                                                  const float* __restrict__ bias,
                                                  const float* __restrict__ resf,
                                                  const u16* __restrict__ resb,
                                                  float* __restrict__ outf,
                                                  u16* __restrict__ outb) {
  __shared__ __align__(16) u16 lds[65536];  // A at 0, B at 32768 (u16 units)
  const int tid = threadIdx.x;
  const int lane = tid & 63, wave = tid >> 6;
  const int lo = lane & 15, hi = lane >> 4;
  const int wm = wave >> 1, wn = wave & 1;
  // XCD swizzle
  int gx = gridDim.x;
  int lin = blockIdx.y * gx + blockIdx.x;
  int nwg = gx * gridDim.y;
  int cpx = nwg >> 3;
  int swz = (lin & 7) * cpx + (lin >> 3);
  int bm0 = (swz / gx) * 128, bn0 = (swz % gx) * 128;
  int T = K >> 7;  // BK = 128

  int rs_ = tid >> 4, ss_ = (tid & 15) ^ (rs_ & 15);
  const u16* srcA = A + (size_t)(bm0 + rs_) * K + ss_ * 8;
  const u16* srcB = Bt + (size_t)(bn0 + rs_) * K + ss_ * 8;
  const size_t i1 = (size_t)32 * K;   // chunk-set 1: +32 rows
  const size_t h1 = (size_t)64 * K;   // half 1: +64 rows
  const int dst0 = wave * 512;
  const int dst1 = 4096 + wave * 512;

  const int rA = wm * 16 + lo;        // local row within A-half
  const int cB = wn * 16 + lo;        // local col base within B-half

  f32x4 acc[2][4] = {};
  bf16x8 a[4], b0[2][4], b1[2][4];

  auto stageA = [&](int buf, int h, int koff) {
    const u16* s = srcA + koff + (h ? h1 : 0);
    u16* d = lds + (buf * 2 + h) * 8192;
    gload_lds16(s, d + dst0);
    gload_lds16(s + i1, d + dst1);
  };
  auto stageB = [&](int buf, int h, int koff) {
    const u16* s = srcB + koff + (h ? h1 : 0);
    u16* d = lds + 32768 + (buf * 2 + h) * 8192;
    gload_lds16(s, d + dst0);
    gload_lds16(s + i1, d + dst1);
  };
  auto loadA_ = [&](int buf, int h) {
    const u16* base = lds + (buf * 2 + h) * 8192 + rA * 128;
#pragma unroll
    for (int kk = 0; kk < 4; kk++)
      a[kk] = *(const bf16x8*)(base + (((kk * 4 + hi) ^ lo) << 3));
  };
  auto loadB_ = [&](bf16x8 (&bb)[2][4], int buf, int g) {
    const u16* base = lds + 32768 + (buf * 2 + g) * 8192 + cB * 128;
#pragma unroll
    for (int n = 0; n < 2; n++)
#pragma unroll
      for (int kk = 0; kk < 4; kk++)
        bb[n][kk] = *(const bf16x8*)(base + n * 4096 + (((kk * 4 + hi) ^ lo) << 3));
  };
  auto mmac = [&](int mt, int g, bf16x8 (&bb)[2][4]) {
    __builtin_amdgcn_s_setprio(1);
#pragma unroll
    for (int n = 0; n < 2; n++)
#pragma unroll
      for (int kk = 0; kk < 4; kk++)
        acc[mt][g * 2 + n] = MFMA16(a[kk], bb[n][kk], acc[mt][g * 2 + n]);
    __builtin_amdgcn_s_setprio(0);
  };

  // prologue: tile 0, order Ah0,Bh0,Bh1,Ah1; Ah0,Bh0 confirmed, Bh1,Ah1 in flight
  stageA(0, 0, 0); stageB(0, 0, 0); stageB(0, 1, 0); stageA(0, 1, 0);
  VMCNT(4);
  __builtin_amdgcn_s_barrier();

  for (int t = 0; t < T; ++t) {
    int cur = t & 1, nxt = cur ^ 1;
    bool more = (t + 1 < T);
    int koff = (t + 1) * 128;
    // P1: a = A-h0, b0 = B-h0; MFMA mt0 x nt{0,1}
    loadA_(cur, 0); loadB_(b0, cur, 0);
    if (more) stageA(nxt, 0, koff);
    __builtin_amdgcn_s_barrier();
    LGKM0();
    __builtin_amdgcn_sched_barrier(0);
    mmac(0, 0, b0);
    __builtin_amdgcn_s_barrier();
    // P2: b1 = B-h1; MFMA mt0 x nt{2,3}
    loadB_(b1, cur, 1);
    if (more) { stageB(nxt, 0, koff); VMCNT(6); } else { VMCNT(2); }
    __builtin_amdgcn_s_barrier();
    LGKM0();
    __builtin_amdgcn_sched_barrier(0);
    mmac(0, 1, b1);
    __builtin_amdgcn_s_barrier();
    // P3: a = A-h1; MFMA mt1 x nt{0,1} (reuse b0)
    loadA_(cur, 1);
    if (more) { stageB(nxt, 1, koff); VMCNT(6); } else { VMCNT(0); }
    __builtin_amdgcn_s_barrier();
    LGKM0();
    __builtin_amdgcn_sched_barrier(0);
    mmac(1, 0, b0);
    __builtin_amdgcn_s_barrier();
    // P4: MFMA mt1 x nt{2,3} (reuse b1)
    if (more) { stageA(nxt, 1, koff); VMCNT(4); }
    __builtin_amdgcn_s_barrier();
    mmac(1, 1, b1);
    __builtin_amdgcn_s_barrier();
  }

  // epilogue
#pragma unroll
  for (int mt = 0; mt < 2; mt++) {
    int gr0 = bm0 + mt * 64 + wm * 16 + hi * 4;
#pragma unroll
    for (int nt = 0; nt < 4; nt++) {
      int gc = bn0 + nt * 32 + wn * 16 + lo;
      float bb = bias[gc];
#pragma unroll
      for (int j = 0; j < 4; j++) {
        int gr = gr0 + j;
        if constexpr (EPR == 0) {
          outb[(size_t)gr * N + gc] =
              f2bf(acc[mt][nt][j] + bb + resf[(size_t)gr * N + gc]);
        } else {
          outf[(size_t)gr * N + gc] =
              acc[mt][nt][j] + bb + bf2f(resb[(size_t)gr * N + gc]);
        }
      }
    }
  }
}

// ------------------------- causal flash attention (paired Q-tiles) -------------------------
// r8 structure (measured best) + T5 setprio around MFMA clusters.
__global__ __launch_bounds__(512, 4) void attn_kernel(const u16* __restrict__ q,
                                                      const u16* __restrict__ k,
                                                      const u16* __restrict__ vt,
                                                      u16* __restrict__ o) {
  __shared__ __align__(16) u16 Ks[2][64 * 64];
  __shared__ __align__(16) u16 Vs[2][64 * 64];
  __shared__ __align__(16) u16 Ps[8][16 * 72];
  int bh = blockIdx.y;
  int pi = blockIdx.x;  // 0..15
  int tid = threadIdx.x, lane = tid & 63, wave = tid >> 6;
  int lo = lane & 15, hi = lane >> 4;
  int grp = wave >> 2;                      // 0: long tile, 1: short tile
  int qblk_w = grp ? pi : (31 - pi);
  int qb0 = qblk_w * 64;
  int nkb = 32 - pi;                        // loop length = long tile's KV count
  const u16* qbase = q + (size_t)bh * 2048 * 64;
  const u16* kbase = k + (size_t)bh * 2048 * 64;
  const u16* vbase = vt + (size_t)bh * 64 * 2048;

  int srow = tid >> 3;
  int ssl = (tid & 7) ^ (srow & 7);         // both-sides XOR swizzle
  int kOff = srow * 64 + ssl * 8;
  int vOff = srow * 2048 + ssl * 8;

  int qrow = qb0 + (wave & 3) * 16 + lo;
  bf16x8 qf0 = *(const bf16x8*)(qbase + (size_t)qrow * 64 + hi * 8);
  bf16x8 qf1 = *(const bf16x8*)(qbase + (size_t)qrow * 64 + 32 + hi * 8);

  float l_r = 0.0f;
  f32x4 of[4] = {};
  u16* Pw = Ps[wave];

  auto stage = [&](int b, int kb) {
    gload_lds16(kbase + (size_t)kb * 4096 + kOff, Ks[b] + wave * 512);
    gload_lds16(vbase + kb * 64 + vOff, Vs[b] + wave * 512);
  };

  stage(0, 0);
  __syncthreads();

  for (int kb = 0; kb < nkb; kb++) {
    int cur = kb & 1;
    if (kb + 1 < nkb) stage(cur ^ 1, kb + 1);
    if (kb <= qblk_w) {
      const u16* Kb = Ks[cur];
      const u16* Vb = Vs[cur];
      f32x4 s4[4] = {};
      __builtin_amdgcn_s_setprio(1);
#pragma unroll
      for (int nt = 0; nt < 4; nt++) {
        int r = nt * 16 + lo, rw = r & 7;
        bf16x8 kf0 = *(const bf16x8*)(Kb + r * 64 + ((hi ^ rw) << 3));
        bf16x8 kf1 = *(const bf16x8*)(Kb + r * 64 + (((hi + 4) ^ rw) << 3));
        s4[nt] = MFMA16(kf0, qf0, s4[nt]);
        s4[nt] = MFMA16(kf1, qf1, s4[nt]);
      }
      __builtin_amdgcn_s_setprio(0);
      float rs = 0.0f;
      bool diag = (kb == qblk_w);
#pragma unroll
      for (int nt = 0; nt < 4; nt++) {
        float e0, e1, e2, e3;
        if (diag) {
          int key = kb * 64 + nt * 16 + hi * 4;
          e0 = (key     > qrow) ? 0.0f : __builtin_amdgcn_exp2f(s4[nt][0]);
          e1 = (key + 1 > qrow) ? 0.0f : __builtin_amdgcn_exp2f(s4[nt][1]);
          e2 = (key + 2 > qrow) ? 0.0f : __builtin_amdgcn_exp2f(s4[nt][2]);
          e3 = (key + 3 > qrow) ? 0.0f : __builtin_amdgcn_exp2f(s4[nt][3]);
        } else {
          e0 = __builtin_amdgcn_exp2f(s4[nt][0]);
          e1 = __builtin_amdgcn_exp2f(s4[nt][1]);
          e2 = __builtin_amdgcn_exp2f(s4[nt][2]);
          e3 = __builtin_amdgcn_exp2f(s4[nt][3]);
        }
        rs += (e0 + e1) + (e2 + e3);
        u32x2 w;
        w.x = cvt_pk_bf16(e0, e1);
        w.y = cvt_pk_bf16(e2, e3);
        *(u32x2*)(Pw + lo * 72 + nt * 16 + hi * 4) = w;
      }
      rs += __shfl_xor(rs, 16);
      rs += __shfl_xor(rs, 32);
      l_r += rs;
      bf16x8 pb0 = *(const bf16x8*)(Pw + lo * 72 + hi * 8);
      bf16x8 pb1 = *(const bf16x8*)(Pw + lo * 72 + 32 + hi * 8);
      __builtin_amdgcn_s_setprio(1);
#pragma unroll
      for (int et = 0; et < 4; et++) {
        int e = et * 16 + lo, ew = e & 7;
        bf16x8 v0 = *(const bf16x8*)(Vb + e * 64 + ((hi ^ ew) << 3));
        bf16x8 v1 = *(const bf16x8*)(Vb + e * 64 + (((hi + 4) ^ ew) << 3));
        of[et] = MFMA16(v0, pb0, of[et]);
        of[et] = MFMA16(v1, pb1, of[et]);
      }
      __builtin_amdgcn_s_setprio(0);
    }
    __syncthreads();
  }
  int hh = bh & 15, bb = bh >> 4;
  float inv = 1.0f / l_r;
  size_t obase = ((size_t)(bb * 2048 + qrow)) * 1024 + hh * 64 + hi * 4;
#pragma unroll
  for (int et = 0; et < 4; et++) {
    u32x2 w;
    w.x = cvt_pk_bf16(of[et][0] * inv, of[et][1] * inv);
    w.y = cvt_pk_bf16(of[et][2] * inv, of[et][3] * inv);
    *(u32x2*)(o + obase + et * 16) = w;
  }
}

extern "C" void kernel_launch(void* const* d_in, const int* in_sizes, int n_in,
                              void* d_out, int out_size, void* d_ws, size_t ws_size,
                              hipStream_t stream) {
  const float* x = (const float*)d_in[0];
  const float* Wq = (const float*)d_in[1];
  const float* Wk = (const float*)d_in[2];
  const float* Wv = (const float*)d_in[3];
  const float* Wo = (const float*)d_in[4];
  const float* bo = (const float*)d_in[5];
  const float* W1 = (const float*)d_in[6];
  const float* b1 = (const float*)d_in[7];
  const float* W2 = (const float*)d_in[8];
  const float* b2 = (const float*)d_in[9];
  const float* g1 = (const float*)d_in[10];
  const float* be1 = (const float*)d_in[11];
  const float* g2 = (const float*)d_in[12];
  const float* be2 = (const float*)d_in[13];
  float* out = (float*)d_out;
  char* ws = (char*)d_ws;
  const size_t MB = 1024ull * 1024ull;

  // workspace map (72MB peak):
  //  0- 8 : h (ln1) -> o (attn out)          [o dead after Wo gemm]
  //  8-14 : BtQKV [dead after QKV gemm]  -> h2 (ln2 out, 8-16)
  // 14-16 : WoT   [dead after Wo gemm]
  // 16-24 : W1T   [dead after FFN1]
  // 24-32 : x1b (bf16 residual)          [Wo gemm .. FFN2]
  // 32-40 : qb    [dead after attn]      -> yb (32-64, FFN1 out)
  // 40-48 : kb
  // 48-56 : vtb
  // 64-72 : W2T   [dead after FFN2]
  u16* h = (u16*)(ws + 0);
  u16* o = h;
  u16* BtQKV = (u16*)(ws + 8 * MB);
  u16* WoT = (u16*)(ws + 14 * MB);
  u16* W1T = (u16*)(ws + 16 * MB);
  u16* x1b = (u16*)(ws + 24 * MB);
  u16* W2T = (u16*)(ws + 64 * MB);
  u16* qb = (u16*)(ws + 32 * MB);
  u16* kb = (u16*)(ws + 40 * MB);
  u16* vtb = (u16*)(ws + 48 * MB);
  u16* h2 = (u16*)(ws + 8 * MB);
  u16* yb = (u16*)(ws + 32 * MB);

  // 1. prep: LN1 + all weight transposes (one launch, vectorized)
  prep_kernel<<<7168, 256, 0, stream>>>(x, g1, be1, h, Wq, Wk, Wv, BtQKV,
                                        Wo, WoT, W1, W1T, W2, W2T);
  // 2. QKV projection (TRANSPOSED): C[feature][token] = BtQKV x h^T;
  //    packed q/k stores, scalar vT. grid (N=4096/256, M=3072/256) = (16,12)
  gemm8p<0><<<dim3(16, 12), 512, 0, stream>>>(BtQKV, h, 3072, 4096, 1024, 1024,
                                              (void*)qb, kb, vtb, nullptr);
  // 3. causal attention -> o (bf16 [B][T][D]); 16 mirrored-paired blocks x 32 bh
  attn_kernel<<<dim3(16, 32), 512, 0, stream>>>(qb, kb, vtb, o);
  // 4. Wo: x1b (bf16) = x + o@Wo + bo, 128^2 8-wave tiles
  gemm128<0><<<dim3(8, 32), 512, 0, stream>>>(o, WoT, 4096, 1024, 1024, bo,
                                              x, nullptr, nullptr, x1b);
  // 5. LN2: x1b (bf16) -> h2 (bf16)
  ln_bf16_kernel<<<4096, 256, 0, stream>>>(x1b, g2, be2, h2);
  // 6. FFN1: y = relu(h2@W1 + b1) (bf16), 256^2 tiles
  gemm8p<2><<<dim3(16, 16), 512, 0, stream>>>(h2, W1T, 4096, 4096, 1024, 1024,
                                              (void*)yb, nullptr, nullptr, b1);
  // 7. FFN2: out (fp32) = x1b + y@W2 + b2, 128^2 8-wave tiles, K=4096
  gemm128<1><<<dim3(8, 32), 512, 0, stream>>>(yb, W2T, 4096, 1024, 4096, b2,
                                              nullptr, x1b, out, nullptr);
}

// Round 21
// 194.030 us; speedup vs baseline: 1.0056x; 1.0056x over previous
//
#include <hip/hip_runtime.h>
#include <stdint.h>

typedef unsigned short u16;
typedef __attribute__((ext_vector_type(8))) short bf16x8;
typedef __attribute__((ext_vector_type(4))) float f32x4;
typedef __attribute__((ext_vector_type(4))) unsigned int u32x4;
typedef __attribute__((ext_vector_type(2))) unsigned int u32x2;
typedef __attribute__((ext_vector_type(4))) unsigned short u16x4;

#define MFMA16(a, b, c) __builtin_amdgcn_mfma_f32_16x16x32_bf16(a, b, c, 0, 0, 0)
#define VMCNT(N) asm volatile("s_waitcnt vmcnt(" #N ")" ::: "memory")
#define LGKM0() asm volatile("s_waitcnt lgkmcnt(0)" ::: "memory")

__device__ __forceinline__ u16 f2bf(float f) {
  union { float f; uint32_t u; } v; v.f = f;
  uint32_t r = v.u + 0x7FFFu + ((v.u >> 16) & 1u);
  return (u16)(r >> 16);
}

__device__ __forceinline__ float bf2f(u16 u) {
  union { uint32_t u; float f; } v; v.u = ((uint32_t)u) << 16;
  return v.f;
}

__device__ __forceinline__ uint32_t cvt_pk_bf16(float a, float b) {
  uint32_t r;
  asm("v_cvt_pk_bf16_f32 %0, %1, %2" : "=v"(r) : "v"(a), "v"(b));
  return r;
}

// async global->LDS, 16B per lane. LDS dest is wave-uniform base + lane*16.
__device__ __forceinline__ void gload_lds16(const u16* g, u16* l) {
  __builtin_amdgcn_global_load_lds((const __attribute__((address_space(1))) void*)(g),
                                   (__attribute__((address_space(3))) void*)(l), 16, 0, 0);
}

// ------------- prep mega-kernel: LN1 + all weight transposes, one launch -------------
__global__ __launch_bounds__(256) void prep_kernel(
    const float* __restrict__ x, const float* __restrict__ g1,
    const float* __restrict__ be1, u16* __restrict__ h,
    const float* __restrict__ Wq, const float* __restrict__ Wk,
    const float* __restrict__ Wv, u16* __restrict__ BtQKV,
    const float* __restrict__ Wo, u16* __restrict__ WoT,
    const float* __restrict__ W1, u16* __restrict__ W1T,
    const float* __restrict__ W2, u16* __restrict__ W2T) {
  __shared__ float ld[64 * 65];
  __shared__ float red[8];
  int bid = blockIdx.x, tid = threadIdx.x;
  if (bid < 4096) {
    int row = bid;
    float4 v = ((const float4*)(x + (size_t)row * 1024))[tid];
    float s = v.x + v.y + v.z + v.w;
    float ss = v.x * v.x + v.y * v.y + v.z * v.z + v.w * v.w;
#pragma unroll
    for (int m = 1; m < 64; m <<= 1) { s += __shfl_xor(s, m); ss += __shfl_xor(ss, m); }
    int wave = tid >> 6, lane = tid & 63;
    if (lane == 0) { red[wave] = s; red[4 + wave] = ss; }
    __syncthreads();
    s = red[0] + red[1] + red[2] + red[3];
    ss = red[4] + red[5] + red[6] + red[7];
    float mean = s * (1.0f / 1024.0f);
    float var = ss * (1.0f / 1024.0f) - mean * mean;
    float rstd = rsqrtf(var + 1e-5f);
    float4 gv = ((const float4*)g1)[tid];
    float4 bv = ((const float4*)be1)[tid];
    u16x4 o;
    o.x = f2bf((v.x - mean) * rstd * gv.x + bv.x);
    o.y = f2bf((v.y - mean) * rstd * gv.y + bv.y);
    o.z = f2bf((v.z - mean) * rstd * gv.z + bv.z);
    o.w = f2bf((v.w - mean) * rstd * gv.w + bv.w);
    *(u16x4*)(h + (size_t)row * 1024 + tid * 4) = o;
    return;
  }
  int bid2 = bid - 4096;
  const float* I;
  u16* O;
  int K, N, n0, k0;
  if (bid2 < 768) {        // QKV heads: 48 heads x 16 k-tiles
    int hb = bid2 >> 4, kt = bid2 & 15;
    int ww = hb >> 4, head = hb & 15;
    I = ((ww == 0) ? Wq : (ww == 1) ? Wk : Wv) + (size_t)head * 65536;
    O = BtQKV + (size_t)ww * 1048576 + (size_t)head * 65536;
    K = 1024; N = 64; k0 = kt * 64; n0 = 0;
  } else if (bid2 < 1024) {  // Wo: 16k x 16n tiles
    int i2 = bid2 - 768;
    I = Wo; O = WoT; K = 1024; N = 1024;
    k0 = (i2 >> 4) * 64; n0 = (i2 & 15) * 64;
  } else if (bid2 < 2048) {  // W1: 16k x 64n tiles
    int i3 = bid2 - 1024;
    I = W1; O = W1T; K = 1024; N = 4096;
    k0 = (i3 >> 6) * 64; n0 = (i3 & 63) * 64;
  } else {                   // W2: 64k x 16n tiles
    int i4 = bid2 - 2048;
    I = W2; O = W2T; K = 4096; N = 1024;
    k0 = (i4 >> 4) * 64; n0 = (i4 & 15) * 64;
  }
  // load: float4 along n, store LDS [k][n] (2-way bank alias: free)
  int nn4 = tid & 15;        // n = nn4*4
#pragma unroll
  for (int it = 0; it < 4; it++) {
    int kk = (tid >> 4) + it * 16;
    float4 v = *(const float4*)(I + (size_t)(k0 + kk) * N + n0 + nn4 * 4);
    float* dst = ld + kk * 65 + nn4 * 4;
    dst[0] = v.x; dst[1] = v.y; dst[2] = v.z; dst[3] = v.w;
  }
  __syncthreads();
  // write: u16x4 along k (lanes 0-15 cover 128B of one out row; 2-way LDS alias)
  int kc = tid & 15;         // k = kc*4
#pragma unroll
  for (int it = 0; it < 4; it++) {
    int n = (tid >> 4) + it * 16;
    u16x4 w;
    w.x = f2bf(ld[(kc * 4 + 0) * 65 + n]);
    w.y = f2bf(ld[(kc * 4 + 1) * 65 + n]);
    w.z = f2bf(ld[(kc * 4 + 2) * 65 + n]);
    w.w = f2bf(ld[(kc * 4 + 3) * 65 + n]);
    *(u16x4*)(O + (size_t)(n0 + n) * K + k0 + kc * 4) = w;
  }
}

// ------- LayerNorm over bf16 input: x1b bf16 [rows][1024] -> h2 bf16 -------
__global__ __launch_bounds__(256) void ln_bf16_kernel(const u16* __restrict__ xb,
                                                      const float* __restrict__ g,
                                                      const float* __restrict__ beta,
                                                      u16* __restrict__ out) {
  int row = blockIdx.x;
  int tid = threadIdx.x;
  u16x4 vr = *(const u16x4*)(xb + (size_t)row * 1024 + tid * 4);
  float v0 = bf2f(vr.x), v1 = bf2f(vr.y), v2 = bf2f(vr.z), v3 = bf2f(vr.w);
  float s = v0 + v1 + v2 + v3;
  float ss = v0 * v0 + v1 * v1 + v2 * v2 + v3 * v3;
#pragma unroll
  for (int m = 1; m < 64; m <<= 1) { s += __shfl_xor(s, m); ss += __shfl_xor(ss, m); }
  __shared__ float red[8];
  int wave = tid >> 6, lane = tid & 63;
  if (lane == 0) { red[wave] = s; red[4 + wave] = ss; }
  __syncthreads();
  s = red[0] + red[1] + red[2] + red[3];
  ss = red[4] + red[5] + red[6] + red[7];
  float mean = s * (1.0f / 1024.0f);
  float var = ss * (1.0f / 1024.0f) - mean * mean;
  float rstd = rsqrtf(var + 1e-5f);
  float4 gv = ((const float4*)g)[tid];
  float4 bv = ((const float4*)beta)[tid];
  u16x4 o;
  o.x = f2bf((v0 - mean) * rstd * gv.x + bv.x);
  o.y = f2bf((v1 - mean) * rstd * gv.y + bv.y);
  o.z = f2bf((v2 - mean) * rstd * gv.z + bv.z);
  o.w = f2bf((v3 - mean) * rstd * gv.w + bv.w);
  *(u16x4*)(out + (size_t)row * 1024 + tid * 4) = o;
}

// ---------------- 256x256 8-phase GEMM: C[M][N] = A[M][K] * Bt[N][K]^T ----------------
// m201-conformant schedule (r13 proven). EP 0: QKV scatter (token-major, r19 best);
// EP 2: relu+bias bf16 (FFN1).
template <int EP>
__global__ __launch_bounds__(512, 2) void gemm8p(const u16* __restrict__ A,
                                                 const u16* __restrict__ Bt,
                                                 int M, int N, int K, int KS,
                                                 void* __restrict__ out0,
                                                 u16* __restrict__ out1,
                                                 u16* __restrict__ out2,
                                                 const float* __restrict__ bias) {
  __shared__ __align__(16) u16 lds[65536];  // A at 0, B at 32768 (u16 units)
  const int tid = threadIdx.x;
  const int lane = tid & 63, wave = tid >> 6;
  const int lo = lane & 15, hi = lane >> 4;
  const int wm = wave >> 2, wn = wave & 3;
  // XCD swizzle
  int gx = gridDim.x;
  int lin = blockIdx.y * gx + blockIdx.x;
  int nwg = gx * gridDim.y;
  int cpx = nwg >> 3;
  int swz = (lin & 7) * cpx + (lin >> 3);
  int bm0 = (swz / gx) * 256, bn0 = (swz % gx) * 256;
  int kbeg = blockIdx.z * KS;
  int T = KS >> 6;

  int rs_ = tid >> 3, ss_ = (tid & 7) ^ (rs_ & 7);
  const u16* srcA = A + (size_t)(bm0 + rs_) * K + kbeg + ss_ * 8;
  const u16* srcB = Bt + (size_t)(bn0 + rs_) * K + kbeg + ss_ * 8;
  const size_t i1 = (size_t)64 * K;
  const size_t h1 = (size_t)128 * K;
  const int dst0 = wave * 512;
  const int dst1 = 4096 + wave * 512;

  const int rpA = wm * 16 + lo;
  const int rpB = wn * 16 + lo;
  const int sp0 = (hi ^ (lo & 7)) * 8;

  f32x4 acc[8][4] = {};
  bf16x8 a[4][2], b0[2][2], b1[2][2];

  auto stageA = [&](int buf, int h, int koff) {
    const u16* s = srcA + koff + (h ? h1 : 0);
    u16* d = lds + (buf * 2 + h) * 8192;
    gload_lds16(s, d + dst0);
    gload_lds16(s + i1, d + dst1);
  };
  auto stageB = [&](int buf, int h, int koff) {
    const u16* s = srcB + koff + (h ? h1 : 0);
    u16* d = lds + 32768 + (buf * 2 + h) * 8192;
    gload_lds16(s, d + dst0);
    gload_lds16(s + i1, d + dst1);
  };
  auto loadA = [&](int buf, int h) {
    const u16* base = lds + (buf * 2 + h) * 8192 + rpA * 64;
#pragma unroll
    for (int m = 0; m < 4; m++) {
      a[m][0] = *(const bf16x8*)(base + m * 2048 + sp0);
      a[m][1] = *(const bf16x8*)(base + m * 2048 + (sp0 ^ 32));
    }
  };
  auto loadB = [&](bf16x8 (&bb)[2][2], int buf, int g) {
    const u16* base = lds + 32768 + (buf * 2 + g) * 8192 + rpB * 64;
#pragma unroll
    for (int n = 0; n < 2; n++) {
      bb[n][0] = *(const bf16x8*)(base + n * 4096 + sp0);
      bb[n][1] = *(const bf16x8*)(base + n * 4096 + (sp0 ^ 32));
    }
  };
  auto mmac = [&](int mh, int np, bf16x8 (&bb)[2][2]) {
    __builtin_amdgcn_s_setprio(1);
#pragma unroll
    for (int m = 0; m < 4; m++)
#pragma unroll
      for (int n = 0; n < 2; n++) {
        acc[mh + m][np + n] = MFMA16(a[m][0], bb[n][0], acc[mh + m][np + n]);
        acc[mh + m][np + n] = MFMA16(a[m][1], bb[n][1], acc[mh + m][np + n]);
      }
    __builtin_amdgcn_s_setprio(0);
  };

  stageA(0, 0, 0); stageB(0, 0, 0); stageB(0, 1, 0); stageA(0, 1, 0);
  VMCNT(4);
  __builtin_amdgcn_s_barrier();

  for (int t = 0; t < T; ++t) {
    int cur = t & 1, nxt = cur ^ 1;
    bool more = (t + 1 < T);
    int koff = (t + 1) * 64;
    // P1
    loadA(cur, 0); loadB(b0, cur, 0);
    if (more) stageA(nxt, 0, koff);
    __builtin_amdgcn_s_barrier();
    LGKM0();
    __builtin_amdgcn_sched_barrier(0);
    mmac(0, 0, b0);
    __builtin_amdgcn_s_barrier();
    // P2
    loadB(b1, cur, 1);
    if (more) { stageB(nxt, 0, koff); VMCNT(6); } else { VMCNT(2); }
    __builtin_amdgcn_s_barrier();
    LGKM0();
    __builtin_amdgcn_sched_barrier(0);
    mmac(0, 2, b1);
    __builtin_amdgcn_s_barrier();
    // P3
    loadA(cur, 1);
    if (more) { stageB(nxt, 1, koff); VMCNT(6); } else { VMCNT(0); }
    __builtin_amdgcn_s_barrier();
    LGKM0();
    __builtin_amdgcn_sched_barrier(0);
    mmac(4, 0, b0);
    __builtin_amdgcn_s_barrier();
    // P4
    if (more) { stageA(nxt, 1, koff); VMCNT(4); }
    __builtin_amdgcn_s_barrier();
    mmac(4, 2, b1);
    __builtin_amdgcn_s_barrier();
  }

  const int sec = (EP == 0) ? (bn0 >> 10) : 0;
#pragma unroll
  for (int mt = 0; mt < 8; mt++) {
    int gr0 = bm0 + (mt >> 2) * 128 + (mt & 3) * 32 + wm * 16 + hi * 4;
#pragma unroll
    for (int nt = 0; nt < 4; nt++) {
      int gc = bn0 + (nt >> 1) * 128 + (nt & 1) * 64 + wn * 16 + lo;
      if constexpr (EP == 0) {
        int b_ = gr0 >> 11, t_ = gr0 & 2047;
        int nn = gc & 1023, h_ = nn >> 6, e_ = nn & 63;
        size_t bh = (size_t)(b_ * 16 + h_);
        if (sec == 2) {  // vT: 4 consecutive t per thread -> one 8B store
          u32x2 w;
          w.x = cvt_pk_bf16(acc[mt][nt][0], acc[mt][nt][1]);
          w.y = cvt_pk_bf16(acc[mt][nt][2], acc[mt][nt][3]);
          *(u32x2*)(out2 + (bh * 64 + e_) * 2048 + t_) = w;
        } else {
          float sc = (sec == 0) ? 0.0450842200f : 1.0f;  // q pre-scale D^-0.5*log2e
          u16* dst = (sec == 0) ? (u16*)out0 : out1;
#pragma unroll
          for (int j = 0; j < 4; j++)
            dst[(bh * 2048 + t_ + j) * 64 + e_] = f2bf(acc[mt][nt][j] * sc);
        }
      } else if constexpr (EP == 2) {
#pragma unroll
        for (int j = 0; j < 4; j++) {
          int gr = gr0 + j;
          float v = acc[mt][nt][j] + bias[gc];
          ((u16*)out0)[(size_t)gr * N + gc] = f2bf(fmaxf(v, 0.0f));
        }
      }
    }
  }
}

// ---- 128x128 8-wave 4-phase GEMM (BK=128), r13 proven schedule ----
// EPR 0 (Wo):   x1b(bf16) = acc + bias + resf(fp32)
// EPR 1 (FFN2): outf(fp32) = acc + bias + bf2f(resb)
template <int EPR>
__global__ __launch_bounds__(512, 2) void gemm128(const u16* __restrict__ A,
                                                  const u16* __restrict__ Bt,
                                                  int M, int N, int K,
                                                  const float* __restrict__ bias,
                                                  const float* __restrict__ resf,
                                                  const u16* __restrict__ resb,
                                                  float* __restrict__ outf,
                                                  u16* __restrict__ outb) {
  __shared__ __align__(16) u16 lds[65536];  // A at 0, B at 32768 (u16 units)
  const int tid = threadIdx.x;
  const int lane = tid & 63, wave = tid >> 6;
  const int lo = lane & 15, hi = lane >> 4;
  const int wm = wave >> 1, wn = wave & 1;
  // XCD swizzle
  int gx = gridDim.x;
  int lin = blockIdx.y * gx + blockIdx.x;
  int nwg = gx * gridDim.y;
  int cpx = nwg >> 3;
  int swz = (lin & 7) * cpx + (lin >> 3);
  int bm0 = (swz / gx) * 128, bn0 = (swz % gx) * 128;
  int T = K >> 7;  // BK = 128

  int rs_ = tid >> 4, ss_ = (tid & 15) ^ (rs_ & 15);
  const u16* srcA = A + (size_t)(bm0 + rs_) * K + ss_ * 8;
  const u16* srcB = Bt + (size_t)(bn0 + rs_) * K + ss_ * 8;
  const size_t i1 = (size_t)32 * K;   // chunk-set 1: +32 rows
  const size_t h1 = (size_t)64 * K;   // half 1: +64 rows
  const int dst0 = wave * 512;
  const int dst1 = 4096 + wave * 512;

  const int rA = wm * 16 + lo;        // local row within A-half
  const int cB = wn * 16 + lo;        // local col base within B-half

  f32x4 acc[2][4] = {};
  bf16x8 a[4], b0[2][4], b1[2][4];

  auto stageA = [&](int buf, int h, int koff) {
    const u16* s = srcA + koff + (h ? h1 : 0);
    u16* d = lds + (buf * 2 + h) * 8192;
    gload_lds16(s, d + dst0);
    gload_lds16(s + i1, d + dst1);
  };
  auto stageB = [&](int buf, int h, int koff) {
    const u16* s = srcB + koff + (h ? h1 : 0);
    u16* d = lds + 32768 + (buf * 2 + h) * 8192;
    gload_lds16(s, d + dst0);
    gload_lds16(s + i1, d + dst1);
  };
  auto loadA_ = [&](int buf, int h) {
    const u16* base = lds + (buf * 2 + h) * 8192 + rA * 128;
#pragma unroll
    for (int kk = 0; kk < 4; kk++)
      a[kk] = *(const bf16x8*)(base + (((kk * 4 + hi) ^ lo) << 3));
  };
  auto loadB_ = [&](bf16x8 (&bb)[2][4], int buf, int g) {
    const u16* base = lds + 32768 + (buf * 2 + g) * 8192 + cB * 128;
#pragma unroll
    for (int n = 0; n < 2; n++)
#pragma unroll
      for (int kk = 0; kk < 4; kk++)
        bb[n][kk] = *(const bf16x8*)(base + n * 4096 + (((kk * 4 + hi) ^ lo) << 3));
  };
  auto mmac = [&](int mt, int g, bf16x8 (&bb)[2][4]) {
    __builtin_amdgcn_s_setprio(1);
#pragma unroll
    for (int n = 0; n < 2; n++)
#pragma unroll
      for (int kk = 0; kk < 4; kk++)
        acc[mt][g * 2 + n] = MFMA16(a[kk], bb[n][kk], acc[mt][g * 2 + n]);
    __builtin_amdgcn_s_setprio(0);
  };

  // prologue: tile 0, order Ah0,Bh0,Bh1,Ah1; Ah0,Bh0 confirmed, Bh1,Ah1 in flight
  stageA(0, 0, 0); stageB(0, 0, 0); stageB(0, 1, 0); stageA(0, 1, 0);
  VMCNT(4);
  __builtin_amdgcn_s_barrier();

  for (int t = 0; t < T; ++t) {
    int cur = t & 1, nxt = cur ^ 1;
    bool more = (t + 1 < T);
    int koff = (t + 1) * 128;
    // P1: a = A-h0, b0 = B-h0; MFMA mt0 x nt{0,1}
    loadA_(cur, 0); loadB_(b0, cur, 0);
    if (more) stageA(nxt, 0, koff);
    __builtin_amdgcn_s_barrier();
    LGKM0();
    __builtin_amdgcn_sched_barrier(0);
    mmac(0, 0, b0);
    __builtin_amdgcn_s_barrier();
    // P2: b1 = B-h1; MFMA mt0 x nt{2,3}
    loadB_(b1, cur, 1);
    if (more) { stageB(nxt, 0, koff); VMCNT(6); } else { VMCNT(2); }
    __builtin_amdgcn_s_barrier();
    LGKM0();
    __builtin_amdgcn_sched_barrier(0);
    mmac(0, 1, b1);
    __builtin_amdgcn_s_barrier();
    // P3: a = A-h1; MFMA mt1 x nt{0,1} (reuse b0)
    loadA_(cur, 1);
    if (more) { stageB(nxt, 1, koff); VMCNT(6); } else { VMCNT(0); }
    __builtin_amdgcn_s_barrier();
    LGKM0();
    __builtin_amdgcn_sched_barrier(0);
    mmac(1, 0, b0);
    __builtin_amdgcn_s_barrier();
    // P4: MFMA mt1 x nt{2,3} (reuse b1)
    if (more) { stageA(nxt, 1, koff); VMCNT(4); }
    __builtin_amdgcn_s_barrier();
    mmac(1, 1, b1);
    __builtin_amdgcn_s_barrier();
  }

  // epilogue
#pragma unroll
  for (int mt = 0; mt < 2; mt++) {
    int gr0 = bm0 + mt * 64 + wm * 16 + hi * 4;
#pragma unroll
    for (int nt = 0; nt < 4; nt++) {
      int gc = bn0 + nt * 32 + wn * 16 + lo;
      float bb = bias[gc];
#pragma unroll
      for (int j = 0; j < 4; j++) {
        int gr = gr0 + j;
        if constexpr (EPR == 0) {
          outb[(size_t)gr * N + gc] =
              f2bf(acc[mt][nt][j] + bb + resf[(size_t)gr * N + gc]);
        } else {
          outf[(size_t)gr * N + gc] =
              acc[mt][nt][j] + bb + bf2f(resb[(size_t)gr * N + gc]);
        }
      }
    }
  }
}

// ------------------------- causal flash attention (paired Q-tiles) -------------------------
// r8 structure (measured best) + T5 setprio around MFMA clusters.
__global__ __launch_bounds__(512, 4) void attn_kernel(const u16* __restrict__ q,
                                                      const u16* __restrict__ k,
                                                      const u16* __restrict__ vt,
                                                      u16* __restrict__ o) {
  __shared__ __align__(16) u16 Ks[2][64 * 64];
  __shared__ __align__(16) u16 Vs[2][64 * 64];
  __shared__ __align__(16) u16 Ps[8][16 * 72];
  int bh = blockIdx.y;
  int pi = blockIdx.x;  // 0..15
  int tid = threadIdx.x, lane = tid & 63, wave = tid >> 6;
  int lo = lane & 15, hi = lane >> 4;
  int grp = wave >> 2;                      // 0: long tile, 1: short tile
  int qblk_w = grp ? pi : (31 - pi);
  int qb0 = qblk_w * 64;
  int nkb = 32 - pi;                        // loop length = long tile's KV count
  const u16* qbase = q + (size_t)bh * 2048 * 64;
  const u16* kbase = k + (size_t)bh * 2048 * 64;
  const u16* vbase = vt + (size_t)bh * 64 * 2048;

  int srow = tid >> 3;
  int ssl = (tid & 7) ^ (srow & 7);         // both-sides XOR swizzle
  int kOff = srow * 64 + ssl * 8;
  int vOff = srow * 2048 + ssl * 8;

  int qrow = qb0 + (wave & 3) * 16 + lo;
  bf16x8 qf0 = *(const bf16x8*)(qbase + (size_t)qrow * 64 + hi * 8);
  bf16x8 qf1 = *(const bf16x8*)(qbase + (size_t)qrow * 64 + 32 + hi * 8);

  float l_r = 0.0f;
  f32x4 of[4] = {};
  u16* Pw = Ps[wave];

  auto stage = [&](int b, int kb) {
    gload_lds16(kbase + (size_t)kb * 4096 + kOff, Ks[b] + wave * 512);
    gload_lds16(vbase + kb * 64 + vOff, Vs[b] + wave * 512);
  };

  stage(0, 0);
  __syncthreads();

  for (int kb = 0; kb < nkb; kb++) {
    int cur = kb & 1;
    if (kb + 1 < nkb) stage(cur ^ 1, kb + 1);
    if (kb <= qblk_w) {
      const u16* Kb = Ks[cur];
      const u16* Vb = Vs[cur];
      f32x4 s4[4] = {};
      __builtin_amdgcn_s_setprio(1);
#pragma unroll
      for (int nt = 0; nt < 4; nt++) {
        int r = nt * 16 + lo, rw = r & 7;
        bf16x8 kf0 = *(const bf16x8*)(Kb + r * 64 + ((hi ^ rw) << 3));
        bf16x8 kf1 = *(const bf16x8*)(Kb + r * 64 + (((hi + 4) ^ rw) << 3));
        s4[nt] = MFMA16(kf0, qf0, s4[nt]);
        s4[nt] = MFMA16(kf1, qf1, s4[nt]);
      }
      __builtin_amdgcn_s_setprio(0);
      float rs = 0.0f;
      bool diag = (kb == qblk_w);
#pragma unroll
      for (int nt = 0; nt < 4; nt++) {
        float e0, e1, e2, e3;
        if (diag) {
          int key = kb * 64 + nt * 16 + hi * 4;
          e0 = (key     > qrow) ? 0.0f : __builtin_amdgcn_exp2f(s4[nt][0]);
          e1 = (key + 1 > qrow) ? 0.0f : __builtin_amdgcn_exp2f(s4[nt][1]);
          e2 = (key + 2 > qrow) ? 0.0f : __builtin_amdgcn_exp2f(s4[nt][2]);
          e3 = (key + 3 > qrow) ? 0.0f : __builtin_amdgcn_exp2f(s4[nt][3]);
        } else {
          e0 = __builtin_amdgcn_exp2f(s4[nt][0]);
          e1 = __builtin_amdgcn_exp2f(s4[nt][1]);
          e2 = __builtin_amdgcn_exp2f(s4[nt][2]);
          e3 = __builtin_amdgcn_exp2f(s4[nt][3]);
        }
        rs += (e0 + e1) + (e2 + e3);
        u32x2 w;
        w.x = cvt_pk_bf16(e0, e1);
        w.y = cvt_pk_bf16(e2, e3);
        *(u32x2*)(Pw + lo * 72 + nt * 16 + hi * 4) = w;
      }
      rs += __shfl_xor(rs, 16);
      rs += __shfl_xor(rs, 32);
      l_r += rs;
      bf16x8 pb0 = *(const bf16x8*)(Pw + lo * 72 + hi * 8);
      bf16x8 pb1 = *(const bf16x8*)(Pw + lo * 72 + 32 + hi * 8);
      __builtin_amdgcn_s_setprio(1);
#pragma unroll
      for (int et = 0; et < 4; et++) {
        int e = et * 16 + lo, ew = e & 7;
        bf16x8 v0 = *(const bf16x8*)(Vb + e * 64 + ((hi ^ ew) << 3));
        bf16x8 v1 = *(const bf16x8*)(Vb + e * 64 + (((hi + 4) ^ ew) << 3));
        of[et] = MFMA16(v0, pb0, of[et]);
        of[et] = MFMA16(v1, pb1, of[et]);
      }
      __builtin_amdgcn_s_setprio(0);
    }
    __syncthreads();
  }
  int hh = bh & 15, bb = bh >> 4;
  float inv = 1.0f / l_r;
  size_t obase = ((size_t)(bb * 2048 + qrow)) * 1024 + hh * 64 + hi * 4;
#pragma unroll
  for (int et = 0; et < 4; et++) {
    u32x2 w;
    w.x = cvt_pk_bf16(of[et][0] * inv, of[et][1] * inv);
    w.y = cvt_pk_bf16(of[et][2] * inv, of[et][3] * inv);
    *(u32x2*)(o + obase + et * 16) = w;
  }
}

extern "C" void kernel_launch(void* const* d_in, const int* in_sizes, int n_in,
                              void* d_out, int out_size, void* d_ws, size_t ws_size,
                              hipStream_t stream) {
  const float* x = (const float*)d_in[0];
  const float* Wq = (const float*)d_in[1];
  const float* Wk = (const float*)d_in[2];
  const float* Wv = (const float*)d_in[3];
  const float* Wo = (const float*)d_in[4];
  const float* bo = (const float*)d_in[5];
  const float* W1 = (const float*)d_in[6];
  const float* b1 = (const float*)d_in[7];
  const float* W2 = (const float*)d_in[8];
  const float* b2 = (const float*)d_in[9];
  const float* g1 = (const float*)d_in[10];
  const float* be1 = (const float*)d_in[11];
  const float* g2 = (const float*)d_in[12];
  const float* be2 = (const float*)d_in[13];
  float* out = (float*)d_out;
  char* ws = (char*)d_ws;
  const size_t MB = 1024ull * 1024ull;

  // workspace map (72MB peak):
  //  0- 8 : h (ln1) -> o (attn out)          [o dead after Wo gemm]
  //  8-14 : BtQKV [dead after QKV gemm]  -> h2 (ln2 out, 8-16)
  // 14-16 : WoT   [dead after Wo gemm]
  // 16-24 : W1T   [dead after FFN1]
  // 24-32 : x1b (bf16 residual)          [Wo gemm .. FFN2]
  // 32-40 : qb    [dead after attn]      -> yb (32-64, FFN1 out)
  // 40-48 : kb
  // 48-56 : vtb
  // 64-72 : W2T   [dead after FFN2]
  u16* h = (u16*)(ws + 0);
  u16* o = h;
  u16* BtQKV = (u16*)(ws + 8 * MB);
  u16* WoT = (u16*)(ws + 14 * MB);
  u16* W1T = (u16*)(ws + 16 * MB);
  u16* x1b = (u16*)(ws + 24 * MB);
  u16* W2T = (u16*)(ws + 64 * MB);
  u16* qb = (u16*)(ws + 32 * MB);
  u16* kb = (u16*)(ws + 40 * MB);
  u16* vtb = (u16*)(ws + 48 * MB);
  u16* h2 = (u16*)(ws + 8 * MB);
  u16* yb = (u16*)(ws + 32 * MB);

  // 1. prep: LN1 + all weight transposes (one launch, vectorized)
  prep_kernel<<<7168, 256, 0, stream>>>(x, g1, be1, h, Wq, Wk, Wv, BtQKV,
                                        Wo, WoT, W1, W1T, W2, W2T);
  // 2. QKV projection: [4096][1024] x [3072][1024]^T, scatter epilogue (q pre-scaled)
  gemm8p<0><<<dim3(12, 16), 512, 0, stream>>>(h, BtQKV, 4096, 3072, 1024, 1024,
                                              (void*)qb, kb, vtb, nullptr);
  // 3. causal attention -> o (bf16 [B][T][D]); 16 mirrored-paired blocks x 32 bh
  attn_kernel<<<dim3(16, 32), 512, 0, stream>>>(qb, kb, vtb, o);
  // 4. Wo: x1b (bf16) = x + o@Wo + bo, 128^2 8-wave tiles
  gemm128<0><<<dim3(8, 32), 512, 0, stream>>>(o, WoT, 4096, 1024, 1024, bo,
                                              x, nullptr, nullptr, x1b);
  // 5. LN2: x1b (bf16) -> h2 (bf16)
  ln_bf16_kernel<<<4096, 256, 0, stream>>>(x1b, g2, be2, h2);
  // 6. FFN1: y = relu(h2@W1 + b1) (bf16), 256^2 tiles
  gemm8p<2><<<dim3(16, 16), 512, 0, stream>>>(h2, W1T, 4096, 4096, 1024, 1024,
                                              (void*)yb, nullptr, nullptr, b1);
  // 7. FFN2: out (fp32) = x1b + y@W2 + b2, 128^2 8-wave tiles, K=4096
  gemm128<1><<<dim3(8, 32), 512, 0, stream>>>(yb, W2T, 4096, 1024, 4096, b2,
                                              nullptr, x1b, out, nullptr);
}

// Round 22
// 191.982 us; speedup vs baseline: 1.0163x; 1.0107x over previous
//
#include <hip/hip_runtime.h>
#include <stdint.h>

typedef unsigned short u16;
typedef __attribute__((ext_vector_type(8))) short bf16x8;
typedef __attribute__((ext_vector_type(4))) float f32x4;
typedef __attribute__((ext_vector_type(4))) unsigned int u32x4;
typedef __attribute__((ext_vector_type(2))) unsigned int u32x2;
typedef __attribute__((ext_vector_type(4))) unsigned short u16x4;

#define MFMA16(a, b, c) __builtin_amdgcn_mfma_f32_16x16x32_bf16(a, b, c, 0, 0, 0)
#define VMCNT(N) asm volatile("s_waitcnt vmcnt(" #N ")" ::: "memory")
#define LGKM0() asm volatile("s_waitcnt lgkmcnt(0)" ::: "memory")

__device__ __forceinline__ u16 f2bf(float f) {
  union { float f; uint32_t u; } v; v.f = f;
  uint32_t r = v.u + 0x7FFFu + ((v.u >> 16) & 1u);
  return (u16)(r >> 16);
}

__device__ __forceinline__ float bf2f(u16 u) {
  union { uint32_t u; float f; } v; v.u = ((uint32_t)u) << 16;
  return v.f;
}

__device__ __forceinline__ uint32_t cvt_pk_bf16(float a, float b) {
  uint32_t r;
  asm("v_cvt_pk_bf16_f32 %0, %1, %2" : "=v"(r) : "v"(a), "v"(b));
  return r;
}

// async global->LDS, 16B per lane. LDS dest is wave-uniform base + lane*16.
__device__ __forceinline__ void gload_lds16(const u16* g, u16* l) {
  __builtin_amdgcn_global_load_lds((const __attribute__((address_space(1))) void*)(g),
                                   (__attribute__((address_space(3))) void*)(l), 16, 0, 0);
}

// ------------- prep mega-kernel: LN1 + all weight transposes, one launch -------------
__global__ __launch_bounds__(256) void prep_kernel(
    const float* __restrict__ x, const float* __restrict__ g1,
    const float* __restrict__ be1, u16* __restrict__ h,
    const float* __restrict__ Wq, const float* __restrict__ Wk,
    const float* __restrict__ Wv, u16* __restrict__ BtQKV,
    const float* __restrict__ Wo, u16* __restrict__ WoT,
    const float* __restrict__ W1, u16* __restrict__ W1T,
    const float* __restrict__ W2, u16* __restrict__ W2T) {
  __shared__ float ld[64 * 65];
  __shared__ float red[8];
  int bid = blockIdx.x, tid = threadIdx.x;
  if (bid < 4096) {
    int row = bid;
    float4 v = ((const float4*)(x + (size_t)row * 1024))[tid];
    float s = v.x + v.y + v.z + v.w;
    float ss = v.x * v.x + v.y * v.y + v.z * v.z + v.w * v.w;
#pragma unroll
    for (int m = 1; m < 64; m <<= 1) { s += __shfl_xor(s, m); ss += __shfl_xor(ss, m); }
    int wave = tid >> 6, lane = tid & 63;
    if (lane == 0) { red[wave] = s; red[4 + wave] = ss; }
    __syncthreads();
    s = red[0] + red[1] + red[2] + red[3];
    ss = red[4] + red[5] + red[6] + red[7];
    float mean = s * (1.0f / 1024.0f);
    float var = ss * (1.0f / 1024.0f) - mean * mean;
    float rstd = rsqrtf(var + 1e-5f);
    float4 gv = ((const float4*)g1)[tid];
    float4 bv = ((const float4*)be1)[tid];
    u16x4 o;
    o.x = f2bf((v.x - mean) * rstd * gv.x + bv.x);
    o.y = f2bf((v.y - mean) * rstd * gv.y + bv.y);
    o.z = f2bf((v.z - mean) * rstd * gv.z + bv.z);
    o.w = f2bf((v.w - mean) * rstd * gv.w + bv.w);
    *(u16x4*)(h + (size_t)row * 1024 + tid * 4) = o;
    return;
  }
  int bid2 = bid - 4096;
  const float* I;
  u16* O;
  int K, N, n0, k0;
  if (bid2 < 768) {        // QKV heads: 48 heads x 16 k-tiles
    int hb = bid2 >> 4, kt = bid2 & 15;
    int ww = hb >> 4, head = hb & 15;
    I = ((ww == 0) ? Wq : (ww == 1) ? Wk : Wv) + (size_t)head * 65536;
    O = BtQKV + (size_t)ww * 1048576 + (size_t)head * 65536;
    K = 1024; N = 64; k0 = kt * 64; n0 = 0;
  } else if (bid2 < 1024) {  // Wo: 16k x 16n tiles
    int i2 = bid2 - 768;
    I = Wo; O = WoT; K = 1024; N = 1024;
    k0 = (i2 >> 4) * 64; n0 = (i2 & 15) * 64;
  } else if (bid2 < 2048) {  // W1: 16k x 64n tiles
    int i3 = bid2 - 1024;
    I = W1; O = W1T; K = 1024; N = 4096;
    k0 = (i3 >> 6) * 64; n0 = (i3 & 63) * 64;
  } else {                   // W2: 64k x 16n tiles
    int i4 = bid2 - 2048;
    I = W2; O = W2T; K = 4096; N = 1024;
    k0 = (i4 >> 4) * 64; n0 = (i4 & 15) * 64;
  }
  // load: float4 along n, store LDS [k][n] (2-way bank alias: free)
  int nn4 = tid & 15;        // n = nn4*4
#pragma unroll
  for (int it = 0; it < 4; it++) {
    int kk = (tid >> 4) + it * 16;
    float4 v = *(const float4*)(I + (size_t)(k0 + kk) * N + n0 + nn4 * 4);
    float* dst = ld + kk * 65 + nn4 * 4;
    dst[0] = v.x; dst[1] = v.y; dst[2] = v.z; dst[3] = v.w;
  }
  __syncthreads();
  // write: u16x4 along k (lanes 0-15 cover 128B of one out row; 2-way LDS alias)
  int kc = tid & 15;         // k = kc*4
#pragma unroll
  for (int it = 0; it < 4; it++) {
    int n = (tid >> 4) + it * 16;
    u16x4 w;
    w.x = f2bf(ld[(kc * 4 + 0) * 65 + n]);
    w.y = f2bf(ld[(kc * 4 + 1) * 65 + n]);
    w.z = f2bf(ld[(kc * 4 + 2) * 65 + n]);
    w.w = f2bf(ld[(kc * 4 + 3) * 65 + n]);
    *(u16x4*)(O + (size_t)(n0 + n) * K + k0 + kc * 4) = w;
  }
}

// ------- LayerNorm over bf16 input: x1b bf16 [rows][1024] -> h2 bf16 -------
__global__ __launch_bounds__(256) void ln_bf16_kernel(const u16* __restrict__ xb,
                                                      const float* __restrict__ g,
                                                      const float* __restrict__ beta,
                                                      u16* __restrict__ out) {
  int row = blockIdx.x;
  int tid = threadIdx.x;
  u16x4 vr = *(const u16x4*)(xb + (size_t)row * 1024 + tid * 4);
  float v0 = bf2f(vr.x), v1 = bf2f(vr.y), v2 = bf2f(vr.z), v3 = bf2f(vr.w);
  float s = v0 + v1 + v2 + v3;
  float ss = v0 * v0 + v1 * v1 + v2 * v2 + v3 * v3;
#pragma unroll
  for (int m = 1; m < 64; m <<= 1) { s += __shfl_xor(s, m); ss += __shfl_xor(ss, m); }
  __shared__ float red[8];
  int wave = tid >> 6, lane = tid & 63;
  if (lane == 0) { red[wave] = s; red[4 + wave] = ss; }
  __syncthreads();
  s = red[0] + red[1] + red[2] + red[3];
  ss = red[4] + red[5] + red[6] + red[7];
  float mean = s * (1.0f / 1024.0f);
  float var = ss * (1.0f / 1024.0f) - mean * mean;
  float rstd = rsqrtf(var + 1e-5f);
  float4 gv = ((const float4*)g)[tid];
  float4 bv = ((const float4*)beta)[tid];
  u16x4 o;
  o.x = f2bf((v0 - mean) * rstd * gv.x + bv.x);
  o.y = f2bf((v1 - mean) * rstd * gv.y + bv.y);
  o.z = f2bf((v2 - mean) * rstd * gv.z + bv.z);
  o.w = f2bf((v3 - mean) * rstd * gv.w + bv.w);
  *(u16x4*)(out + (size_t)row * 1024 + tid * 4) = o;
}

// ---------------- 256x256 8-phase GEMM: C[M][N] = A[M][K] * Bt[N][K]^T ----------------
// m201-conformant schedule (r13 proven). EP 0: QKV scatter (token-major, r19 best);
// EP 2: relu+bias bf16 (FFN1).
template <int EP>
__global__ __launch_bounds__(512, 2) void gemm8p(const u16* __restrict__ A,
                                                 const u16* __restrict__ Bt,
                                                 int M, int N, int K, int KS,
                                                 void* __restrict__ out0,
                                                 u16* __restrict__ out1,
                                                 u16* __restrict__ out2,
                                                 const float* __restrict__ bias) {
  __shared__ __align__(16) u16 lds[65536];  // A at 0, B at 32768 (u16 units)
  const int tid = threadIdx.x;
  const int lane = tid & 63, wave = tid >> 6;
  const int lo = lane & 15, hi = lane >> 4;
  const int wm = wave >> 2, wn = wave & 3;
  // XCD swizzle
  int gx = gridDim.x;
  int lin = blockIdx.y * gx + blockIdx.x;
  int nwg = gx * gridDim.y;
  int cpx = nwg >> 3;
  int swz = (lin & 7) * cpx + (lin >> 3);
  int bm0 = (swz / gx) * 256, bn0 = (swz % gx) * 256;
  int kbeg = blockIdx.z * KS;
  int T = KS >> 6;

  int rs_ = tid >> 3, ss_ = (tid & 7) ^ (rs_ & 7);
  const u16* srcA = A + (size_t)(bm0 + rs_) * K + kbeg + ss_ * 8;
  const u16* srcB = Bt + (size_t)(bn0 + rs_) * K + kbeg + ss_ * 8;
  const size_t i1 = (size_t)64 * K;
  const size_t h1 = (size_t)128 * K;
  const int dst0 = wave * 512;
  const int dst1 = 4096 + wave * 512;

  const int rpA = wm * 16 + lo;
  const int rpB = wn * 16 + lo;
  const int sp0 = (hi ^ (lo & 7)) * 8;

  f32x4 acc[8][4] = {};
  bf16x8 a[4][2], b0[2][2], b1[2][2];

  auto stageA = [&](int buf, int h, int koff) {
    const u16* s = srcA + koff + (h ? h1 : 0);
    u16* d = lds + (buf * 2 + h) * 8192;
    gload_lds16(s, d + dst0);
    gload_lds16(s + i1, d + dst1);
  };
  auto stageB = [&](int buf, int h, int koff) {
    const u16* s = srcB + koff + (h ? h1 : 0);
    u16* d = lds + 32768 + (buf * 2 + h) * 8192;
    gload_lds16(s, d + dst0);
    gload_lds16(s + i1, d + dst1);
  };
  auto loadA = [&](int buf, int h) {
    const u16* base = lds + (buf * 2 + h) * 8192 + rpA * 64;
#pragma unroll
    for (int m = 0; m < 4; m++) {
      a[m][0] = *(const bf16x8*)(base + m * 2048 + sp0);
      a[m][1] = *(const bf16x8*)(base + m * 2048 + (sp0 ^ 32));
    }
  };
  auto loadB = [&](bf16x8 (&bb)[2][2], int buf, int g) {
    const u16* base = lds + 32768 + (buf * 2 + g) * 8192 + rpB * 64;
#pragma unroll
    for (int n = 0; n < 2; n++) {
      bb[n][0] = *(const bf16x8*)(base + n * 4096 + sp0);
      bb[n][1] = *(const bf16x8*)(base + n * 4096 + (sp0 ^ 32));
    }
  };
  auto mmac = [&](int mh, int np, bf16x8 (&bb)[2][2]) {
    __builtin_amdgcn_s_setprio(1);
#pragma unroll
    for (int m = 0; m < 4; m++)
#pragma unroll
      for (int n = 0; n < 2; n++) {
        acc[mh + m][np + n] = MFMA16(a[m][0], bb[n][0], acc[mh + m][np + n]);
        acc[mh + m][np + n] = MFMA16(a[m][1], bb[n][1], acc[mh + m][np + n]);
      }
    __builtin_amdgcn_s_setprio(0);
  };

  stageA(0, 0, 0); stageB(0, 0, 0); stageB(0, 1, 0); stageA(0, 1, 0);
  VMCNT(4);
  __builtin_amdgcn_s_barrier();

  for (int t = 0; t < T; ++t) {
    int cur = t & 1, nxt = cur ^ 1;
    bool more = (t + 1 < T);
    int koff = (t + 1) * 64;
    // P1
    loadA(cur, 0); loadB(b0, cur, 0);
    if (more) stageA(nxt, 0, koff);
    __builtin_amdgcn_s_barrier();
    LGKM0();
    __builtin_amdgcn_sched_barrier(0);
    mmac(0, 0, b0);
    __builtin_amdgcn_s_barrier();
    // P2
    loadB(b1, cur, 1);
    if (more) { stageB(nxt, 0, koff); VMCNT(6); } else { VMCNT(2); }
    __builtin_amdgcn_s_barrier();
    LGKM0();
    __builtin_amdgcn_sched_barrier(0);
    mmac(0, 2, b1);
    __builtin_amdgcn_s_barrier();
    // P3
    loadA(cur, 1);
    if (more) { stageB(nxt, 1, koff); VMCNT(6); } else { VMCNT(0); }
    __builtin_amdgcn_s_barrier();
    LGKM0();
    __builtin_amdgcn_sched_barrier(0);
    mmac(4, 0, b0);
    __builtin_amdgcn_s_barrier();
    // P4
    if (more) { stageA(nxt, 1, koff); VMCNT(4); }
    __builtin_amdgcn_s_barrier();
    mmac(4, 2, b1);
    __builtin_amdgcn_s_barrier();
  }

  const int sec = (EP == 0) ? (bn0 >> 10) : 0;
#pragma unroll
  for (int mt = 0; mt < 8; mt++) {
    int gr0 = bm0 + (mt >> 2) * 128 + (mt & 3) * 32 + wm * 16 + hi * 4;
#pragma unroll
    for (int nt = 0; nt < 4; nt++) {
      int gc = bn0 + (nt >> 1) * 128 + (nt & 1) * 64 + wn * 16 + lo;
      if constexpr (EP == 0) {
        int b_ = gr0 >> 11, t_ = gr0 & 2047;
        int nn = gc & 1023, h_ = nn >> 6, e_ = nn & 63;
        size_t bh = (size_t)(b_ * 16 + h_);
        if (sec == 2) {  // vT: 4 consecutive t per thread -> one 8B store
          u32x2 w;
          w.x = cvt_pk_bf16(acc[mt][nt][0], acc[mt][nt][1]);
          w.y = cvt_pk_bf16(acc[mt][nt][2], acc[mt][nt][3]);
          *(u32x2*)(out2 + (bh * 64 + e_) * 2048 + t_) = w;
        } else {
          float sc = (sec == 0) ? 0.0450842200f : 1.0f;  // q pre-scale D^-0.5*log2e
          u16* dst = (sec == 0) ? (u16*)out0 : out1;
#pragma unroll
          for (int j = 0; j < 4; j++)
            dst[(bh * 2048 + t_ + j) * 64 + e_] = f2bf(acc[mt][nt][j] * sc);
        }
      } else if constexpr (EP == 2) {
#pragma unroll
        for (int j = 0; j < 4; j++) {
          int gr = gr0 + j;
          float v = acc[mt][nt][j] + bias[gc];
          ((u16*)out0)[(size_t)gr * N + gc] = f2bf(fmaxf(v, 0.0f));
        }
      }
    }
  }
}

// ---- 128x128 8-wave 4-phase GEMM (BK=128), r13 proven schedule ----
// EPR 0 (Wo):   x1b(bf16) = acc + bias + resf(fp32)
// EPR 1 (FFN2): outf(fp32) = acc + bias + bf2f(resb)
template <int EPR>
__global__ __launch_bounds__(512, 2) void gemm128(const u16* __restrict__ A,
                                                  const u16* __restrict__ Bt,
                                                  int M, int N, int K,
                                                  const float* __restrict__ bias,
                                                  const float* __restrict__ resf,
                                                  const u16* __restrict__ resb,
                                                  float* __restrict__ outf,
                                                  u16* __restrict__ outb) {
  __shared__ __align__(16) u16 lds[65536];  // A at 0, B at 32768 (u16 units)
  const int tid = threadIdx.x;
  const int lane = tid & 63, wave = tid >> 6;
  const int lo = lane & 15, hi = lane >> 4;
  const int wm = wave >> 1, wn = wave & 1;
  // XCD swizzle
  int gx = gridDim.x;
  int lin = blockIdx.y * gx + blockIdx.x;
  int nwg = gx * gridDim.y;
  int cpx = nwg >> 3;
  int swz = (lin & 7) * cpx + (lin >> 3);
  int bm0 = (swz / gx) * 128, bn0 = (swz % gx) * 128;
  int T = K >> 7;  // BK = 128

  int rs_ = tid >> 4, ss_ = (tid & 15) ^ (rs_ & 15);
  const u16* srcA = A + (size_t)(bm0 + rs_) * K + ss_ * 8;
  const u16* srcB = Bt + (size_t)(bn0 + rs_) * K + ss_ * 8;
  const size_t i1 = (size_t)32 * K;   // chunk-set 1: +32 rows
  const size_t h1 = (size_t)64 * K;   // half 1: +64 rows
  const int dst0 = wave * 512;
  const int dst1 = 4096 + wave * 512;

  const int rA = wm * 16 + lo;        // local row within A-half
  const int cB = wn * 16 + lo;        // local col base within B-half

  f32x4 acc[2][4] = {};
  bf16x8 a[4], b0[2][4], b1[2][4];

  auto stageA = [&](int buf, int h, int koff) {
    const u16* s = srcA + koff + (h ? h1 : 0);
    u16* d = lds + (buf * 2 + h) * 8192;
    gload_lds16(s, d + dst0);
    gload_lds16(s + i1, d + dst1);
  };
  auto stageB = [&](int buf, int h, int koff) {
    const u16* s = srcB + koff + (h ? h1 : 0);
    u16* d = lds + 32768 + (buf * 2 + h) * 8192;
    gload_lds16(s, d + dst0);
    gload_lds16(s + i1, d + dst1);
  };
  auto loadA_ = [&](int buf, int h) {
    const u16* base = lds + (buf * 2 + h) * 8192 + rA * 128;
#pragma unroll
    for (int kk = 0; kk < 4; kk++)
      a[kk] = *(const bf16x8*)(base + (((kk * 4 + hi) ^ lo) << 3));
  };
  auto loadB_ = [&](bf16x8 (&bb)[2][4], int buf, int g) {
    const u16* base = lds + 32768 + (buf * 2 + g) * 8192 + cB * 128;
#pragma unroll
    for (int n = 0; n < 2; n++)
#pragma unroll
      for (int kk = 0; kk < 4; kk++)
        bb[n][kk] = *(const bf16x8*)(base + n * 4096 + (((kk * 4 + hi) ^ lo) << 3));
  };
  auto mmac = [&](int mt, int g, bf16x8 (&bb)[2][4]) {
    __builtin_amdgcn_s_setprio(1);
#pragma unroll
    for (int n = 0; n < 2; n++)
#pragma unroll
      for (int kk = 0; kk < 4; kk++)
        acc[mt][g * 2 + n] = MFMA16(a[kk], bb[n][kk], acc[mt][g * 2 + n]);
    __builtin_amdgcn_s_setprio(0);
  };

  // prologue: tile 0, order Ah0,Bh0,Bh1,Ah1; Ah0,Bh0 confirmed, Bh1,Ah1 in flight
  stageA(0, 0, 0); stageB(0, 0, 0); stageB(0, 1, 0); stageA(0, 1, 0);
  VMCNT(4);
  __builtin_amdgcn_s_barrier();

  for (int t = 0; t < T; ++t) {
    int cur = t & 1, nxt = cur ^ 1;
    bool more = (t + 1 < T);
    int koff = (t + 1) * 128;
    // P1: a = A-h0, b0 = B-h0; MFMA mt0 x nt{0,1}
    loadA_(cur, 0); loadB_(b0, cur, 0);
    if (more) stageA(nxt, 0, koff);
    __builtin_amdgcn_s_barrier();
    LGKM0();
    __builtin_amdgcn_sched_barrier(0);
    mmac(0, 0, b0);
    __builtin_amdgcn_s_barrier();
    // P2: b1 = B-h1; MFMA mt0 x nt{2,3}
    loadB_(b1, cur, 1);
    if (more) { stageB(nxt, 0, koff); VMCNT(6); } else { VMCNT(2); }
    __builtin_amdgcn_s_barrier();
    LGKM0();
    __builtin_amdgcn_sched_barrier(0);
    mmac(0, 1, b1);
    __builtin_amdgcn_s_barrier();
    // P3: a = A-h1; MFMA mt1 x nt{0,1} (reuse b0)
    loadA_(cur, 1);
    if (more) { stageB(nxt, 1, koff); VMCNT(6); } else { VMCNT(0); }
    __builtin_amdgcn_s_barrier();
    LGKM0();
    __builtin_amdgcn_sched_barrier(0);
    mmac(1, 0, b0);
    __builtin_amdgcn_s_barrier();
    // P4: MFMA mt1 x nt{2,3} (reuse b1)
    if (more) { stageA(nxt, 1, koff); VMCNT(4); }
    __builtin_amdgcn_s_barrier();
    mmac(1, 1, b1);
    __builtin_amdgcn_s_barrier();
  }

  // epilogue
#pragma unroll
  for (int mt = 0; mt < 2; mt++) {
    int gr0 = bm0 + mt * 64 + wm * 16 + hi * 4;
#pragma unroll
    for (int nt = 0; nt < 4; nt++) {
      int gc = bn0 + nt * 32 + wn * 16 + lo;
      float bb = bias[gc];
#pragma unroll
      for (int j = 0; j < 4; j++) {
        int gr = gr0 + j;
        if constexpr (EPR == 0) {
          outb[(size_t)gr * N + gc] =
              f2bf(acc[mt][nt][j] + bb + resf[(size_t)gr * N + gc]);
        } else {
          outf[(size_t)gr * N + gc] =
              acc[mt][nt][j] + bb + bf2f(resb[(size_t)gr * N + gc]);
        }
      }
    }
  }
}

// ------------------------- causal flash attention (paired Q-tiles) -------------------------
// r8 structure + T5 setprio. Grid TRANSPOSED for XCD K/V locality: x=bh (32), y=pi (16).
// linear = pi*32 + bh; 32 % 8 == 0 => all 16 blocks of a bh land on XCD bh%8 under
// round-robin dispatch -> each bh's K/V (512KB) fetched into ONE L2 instead of 8.
// Also dispatches pi=0 (longest) blocks for all bh first.
__global__ __launch_bounds__(512, 4) void attn_kernel(const u16* __restrict__ q,
                                                      const u16* __restrict__ k,
                                                      const u16* __restrict__ vt,
                                                      u16* __restrict__ o) {
  __shared__ __align__(16) u16 Ks[2][64 * 64];
  __shared__ __align__(16) u16 Vs[2][64 * 64];
  __shared__ __align__(16) u16 Ps[8][16 * 72];
  int bh = blockIdx.x;                      // 0..31 (fast dim -> XCD = bh%8)
  int pi = blockIdx.y;                      // 0..15 (slow dim: pi=0 dispatches first)
  int tid = threadIdx.x, lane = tid & 63, wave = tid >> 6;
  int lo = lane & 15, hi = lane >> 4;
  int grp = wave >> 2;                      // 0: long tile, 1: short tile
  int qblk_w = grp ? pi : (31 - pi);
  int qb0 = qblk_w * 64;
  int nkb = 32 - pi;                        // loop length = long tile's KV count
  const u16* qbase = q + (size_t)bh * 2048 * 64;
  const u16* kbase = k + (size_t)bh * 2048 * 64;
  const u16* vbase = vt + (size_t)bh * 64 * 2048;

  int srow = tid >> 3;
  int ssl = (tid & 7) ^ (srow & 7);         // both-sides XOR swizzle
  int kOff = srow * 64 + ssl * 8;
  int vOff = srow * 2048 + ssl * 8;

  int qrow = qb0 + (wave & 3) * 16 + lo;
  bf16x8 qf0 = *(const bf16x8*)(qbase + (size_t)qrow * 64 + hi * 8);
  bf16x8 qf1 = *(const bf16x8*)(qbase + (size_t)qrow * 64 + 32 + hi * 8);

  float l_r = 0.0f;
  f32x4 of[4] = {};
  u16* Pw = Ps[wave];

  auto stage = [&](int b, int kb) {
    gload_lds16(kbase + (size_t)kb * 4096 + kOff, Ks[b] + wave * 512);
    gload_lds16(vbase + kb * 64 + vOff, Vs[b] + wave * 512);
  };

  stage(0, 0);
  __syncthreads();

  for (int kb = 0; kb < nkb; kb++) {
    int cur = kb & 1;
    if (kb + 1 < nkb) stage(cur ^ 1, kb + 1);
    if (kb <= qblk_w) {
      const u16* Kb = Ks[cur];
      const u16* Vb = Vs[cur];
      f32x4 s4[4] = {};
      __builtin_amdgcn_s_setprio(1);
#pragma unroll
      for (int nt = 0; nt < 4; nt++) {
        int r = nt * 16 + lo, rw = r & 7;
        bf16x8 kf0 = *(const bf16x8*)(Kb + r * 64 + ((hi ^ rw) << 3));
        bf16x8 kf1 = *(const bf16x8*)(Kb + r * 64 + (((hi + 4) ^ rw) << 3));
        s4[nt] = MFMA16(kf0, qf0, s4[nt]);
        s4[nt] = MFMA16(kf1, qf1, s4[nt]);
      }
      __builtin_amdgcn_s_setprio(0);
      float rs = 0.0f;
      bool diag = (kb == qblk_w);
#pragma unroll
      for (int nt = 0; nt < 4; nt++) {
        float e0, e1, e2, e3;
        if (diag) {
          int key = kb * 64 + nt * 16 + hi * 4;
          e0 = (key     > qrow) ? 0.0f : __builtin_amdgcn_exp2f(s4[nt][0]);
          e1 = (key + 1 > qrow) ? 0.0f : __builtin_amdgcn_exp2f(s4[nt][1]);
          e2 = (key + 2 > qrow) ? 0.0f : __builtin_amdgcn_exp2f(s4[nt][2]);
          e3 = (key + 3 > qrow) ? 0.0f : __builtin_amdgcn_exp2f(s4[nt][3]);
        } else {
          e0 = __builtin_amdgcn_exp2f(s4[nt][0]);
          e1 = __builtin_amdgcn_exp2f(s4[nt][1]);
          e2 = __builtin_amdgcn_exp2f(s4[nt][2]);
          e3 = __builtin_amdgcn_exp2f(s4[nt][3]);
        }
        rs += (e0 + e1) + (e2 + e3);
        u32x2 w;
        w.x = cvt_pk_bf16(e0, e1);
        w.y = cvt_pk_bf16(e2, e3);
        *(u32x2*)(Pw + lo * 72 + nt * 16 + hi * 4) = w;
      }
      rs += __shfl_xor(rs, 16);
      rs += __shfl_xor(rs, 32);
      l_r += rs;
      bf16x8 pb0 = *(const bf16x8*)(Pw + lo * 72 + hi * 8);
      bf16x8 pb1 = *(const bf16x8*)(Pw + lo * 72 + 32 + hi * 8);
      __builtin_amdgcn_s_setprio(1);
#pragma unroll
      for (int et = 0; et < 4; et++) {
        int e = et * 16 + lo, ew = e & 7;
        bf16x8 v0 = *(const bf16x8*)(Vb + e * 64 + ((hi ^ ew) << 3));
        bf16x8 v1 = *(const bf16x8*)(Vb + e * 64 + (((hi + 4) ^ ew) << 3));
        of[et] = MFMA16(v0, pb0, of[et]);
        of[et] = MFMA16(v1, pb1, of[et]);
      }
      __builtin_amdgcn_s_setprio(0);
    }
    __syncthreads();
  }
  int hh = bh & 15, bb = bh >> 4;
  float inv = 1.0f / l_r;
  size_t obase = ((size_t)(bb * 2048 + qrow)) * 1024 + hh * 64 + hi * 4;
#pragma unroll
  for (int et = 0; et < 4; et++) {
    u32x2 w;
    w.x = cvt_pk_bf16(of[et][0] * inv, of[et][1] * inv);
    w.y = cvt_pk_bf16(of[et][2] * inv, of[et][3] * inv);
    *(u32x2*)(o + obase + et * 16) = w;
  }
}

extern "C" void kernel_launch(void* const* d_in, const int* in_sizes, int n_in,
                              void* d_out, int out_size, void* d_ws, size_t ws_size,
                              hipStream_t stream) {
  const float* x = (const float*)d_in[0];
  const float* Wq = (const float*)d_in[1];
  const float* Wk = (const float*)d_in[2];
  const float* Wv = (const float*)d_in[3];
  const float* Wo = (const float*)d_in[4];
  const float* bo = (const float*)d_in[5];
  const float* W1 = (const float*)d_in[6];
  const float* b1 = (const float*)d_in[7];
  const float* W2 = (const float*)d_in[8];
  const float* b2 = (const float*)d_in[9];
  const float* g1 = (const float*)d_in[10];
  const float* be1 = (const float*)d_in[11];
  const float* g2 = (const float*)d_in[12];
  const float* be2 = (const float*)d_in[13];
  float* out = (float*)d_out;
  char* ws = (char*)d_ws;
  const size_t MB = 1024ull * 1024ull;

  // workspace map (72MB peak):
  //  0- 8 : h (ln1) -> o (attn out)          [o dead after Wo gemm]
  //  8-14 : BtQKV [dead after QKV gemm]  -> h2 (ln2 out, 8-16)
  // 14-16 : WoT   [dead after Wo gemm]
  // 16-24 : W1T   [dead after FFN1]
  // 24-32 : x1b (bf16 residual)          [Wo gemm .. FFN2]
  // 32-40 : qb    [dead after attn]      -> yb (32-64, FFN1 out)
  // 40-48 : kb
  // 48-56 : vtb
  // 64-72 : W2T   [dead after FFN2]
  u16* h = (u16*)(ws + 0);
  u16* o = h;
  u16* BtQKV = (u16*)(ws + 8 * MB);
  u16* WoT = (u16*)(ws + 14 * MB);
  u16* W1T = (u16*)(ws + 16 * MB);
  u16* x1b = (u16*)(ws + 24 * MB);
  u16* W2T = (u16*)(ws + 64 * MB);
  u16* qb = (u16*)(ws + 32 * MB);
  u16* kb = (u16*)(ws + 40 * MB);
  u16* vtb = (u16*)(ws + 48 * MB);
  u16* h2 = (u16*)(ws + 8 * MB);
  u16* yb = (u16*)(ws + 32 * MB);

  // 1. prep: LN1 + all weight transposes (one launch, vectorized)
  prep_kernel<<<7168, 256, 0, stream>>>(x, g1, be1, h, Wq, Wk, Wv, BtQKV,
                                        Wo, WoT, W1, W1T, W2, W2T);
  // 2. QKV projection: [4096][1024] x [3072][1024]^T, scatter epilogue (q pre-scaled)
  gemm8p<0><<<dim3(12, 16), 512, 0, stream>>>(h, BtQKV, 4096, 3072, 1024, 1024,
                                              (void*)qb, kb, vtb, nullptr);
  // 3. causal attention -> o; grid (bh=32, pi=16): per-bh K/V pinned to one XCD
  attn_kernel<<<dim3(32, 16), 512, 0, stream>>>(qb, kb, vtb, o);
  // 4. Wo: x1b (bf16) = x + o@Wo + bo, 128^2 8-wave tiles
  gemm128<0><<<dim3(8, 32), 512, 0, stream>>>(o, WoT, 4096, 1024, 1024, bo,
                                              x, nullptr, nullptr, x1b);
  // 5. LN2: x1b (bf16) -> h2 (bf16)
  ln_bf16_kernel<<<4096, 256, 0, stream>>>(x1b, g2, be2, h2);
  // 6. FFN1: y = relu(h2@W1 + b1) (bf16), 256^2 tiles
  gemm8p<2><<<dim3(16, 16), 512, 0, stream>>>(h2, W1T, 4096, 4096, 1024, 1024,
                                              (void*)yb, nullptr, nullptr, b1);
  // 7. FFN2: out (fp32) = x1b + y@W2 + b2, 128^2 8-wave tiles, K=4096
  gemm128<1><<<dim3(8, 32), 512, 0, stream>>>(yb, W2T, 4096, 1024, 4096, b2,
                                              nullptr, x1b, out, nullptr);
}

// Round 23
// 191.564 us; speedup vs baseline: 1.0185x; 1.0022x over previous
//
#include <hip/hip_runtime.h>
#include <stdint.h>

typedef unsigned short u16;
typedef __attribute__((ext_vector_type(8))) short bf16x8;
typedef __attribute__((ext_vector_type(4))) float f32x4;
typedef __attribute__((ext_vector_type(4))) unsigned int u32x4;
typedef __attribute__((ext_vector_type(2))) unsigned int u32x2;
typedef __attribute__((ext_vector_type(4))) unsigned short u16x4;

#define MFMA16(a, b, c) __builtin_amdgcn_mfma_f32_16x16x32_bf16(a, b, c, 0, 0, 0)
#define VMCNT(N) asm volatile("s_waitcnt vmcnt(" #N ")" ::: "memory")
#define LGKM0() asm volatile("s_waitcnt lgkmcnt(0)" ::: "memory")

__device__ __forceinline__ u16 f2bf(float f) {
  union { float f; uint32_t u; } v; v.f = f;
  uint32_t r = v.u + 0x7FFFu + ((v.u >> 16) & 1u);
  return (u16)(r >> 16);
}

__device__ __forceinline__ float bf2f(u16 u) {
  union { uint32_t u; float f; } v; v.u = ((uint32_t)u) << 16;
  return v.f;
}

__device__ __forceinline__ uint32_t cvt_pk_bf16(float a, float b) {
  uint32_t r;
  asm("v_cvt_pk_bf16_f32 %0, %1, %2" : "=v"(r) : "v"(a), "v"(b));
  return r;
}

// async global->LDS, 16B per lane. LDS dest is wave-uniform base + lane*16.
__device__ __forceinline__ void gload_lds16(const u16* g, u16* l) {
  __builtin_amdgcn_global_load_lds((const __attribute__((address_space(1))) void*)(g),
                                   (__attribute__((address_space(3))) void*)(l), 16, 0, 0);
}

// ------------- prep mega-kernel: LN1 + all weight transposes, one launch -------------
__global__ __launch_bounds__(256) void prep_kernel(
    const float* __restrict__ x, const float* __restrict__ g1,
    const float* __restrict__ be1, u16* __restrict__ h,
    const float* __restrict__ Wq, const float* __restrict__ Wk,
    const float* __restrict__ Wv, u16* __restrict__ BtQKV,
    const float* __restrict__ Wo, u16* __restrict__ WoT,
    const float* __restrict__ W1, u16* __restrict__ W1T,
    const float* __restrict__ W2, u16* __restrict__ W2T) {
  __shared__ float ld[64 * 65];
  __shared__ float red[8];
  int bid = blockIdx.x, tid = threadIdx.x;
  if (bid < 4096) {
    int row = bid;
    float4 v = ((const float4*)(x + (size_t)row * 1024))[tid];
    float s = v.x + v.y + v.z + v.w;
    float ss = v.x * v.x + v.y * v.y + v.z * v.z + v.w * v.w;
#pragma unroll
    for (int m = 1; m < 64; m <<= 1) { s += __shfl_xor(s, m); ss += __shfl_xor(ss, m); }
    int wave = tid >> 6, lane = tid & 63;
    if (lane == 0) { red[wave] = s; red[4 + wave] = ss; }
    __syncthreads();
    s = red[0] + red[1] + red[2] + red[3];
    ss = red[4] + red[5] + red[6] + red[7];
    float mean = s * (1.0f / 1024.0f);
    float var = ss * (1.0f / 1024.0f) - mean * mean;
    float rstd = rsqrtf(var + 1e-5f);
    float4 gv = ((const float4*)g1)[tid];
    float4 bv = ((const float4*)be1)[tid];
    u16x4 o;
    o.x = f2bf((v.x - mean) * rstd * gv.x + bv.x);
    o.y = f2bf((v.y - mean) * rstd * gv.y + bv.y);
    o.z = f2bf((v.z - mean) * rstd * gv.z + bv.z);
    o.w = f2bf((v.w - mean) * rstd * gv.w + bv.w);
    *(u16x4*)(h + (size_t)row * 1024 + tid * 4) = o;
    return;
  }
  int bid2 = bid - 4096;
  const float* I;
  u16* O;
  int K, N, n0, k0;
  if (bid2 < 768) {        // QKV heads: 48 heads x 16 k-tiles
    int hb = bid2 >> 4, kt = bid2 & 15;
    int ww = hb >> 4, head = hb & 15;
    I = ((ww == 0) ? Wq : (ww == 1) ? Wk : Wv) + (size_t)head * 65536;
    O = BtQKV + (size_t)ww * 1048576 + (size_t)head * 65536;
    K = 1024; N = 64; k0 = kt * 64; n0 = 0;
  } else if (bid2 < 1024) {  // Wo: 16k x 16n tiles
    int i2 = bid2 - 768;
    I = Wo; O = WoT; K = 1024; N = 1024;
    k0 = (i2 >> 4) * 64; n0 = (i2 & 15) * 64;
  } else if (bid2 < 2048) {  // W1: 16k x 64n tiles
    int i3 = bid2 - 1024;
    I = W1; O = W1T; K = 1024; N = 4096;
    k0 = (i3 >> 6) * 64; n0 = (i3 & 63) * 64;
  } else {                   // W2: 64k x 16n tiles
    int i4 = bid2 - 2048;
    I = W2; O = W2T; K = 4096; N = 1024;
    k0 = (i4 >> 4) * 64; n0 = (i4 & 15) * 64;
  }
  // load: float4 along n, store LDS [k][n] (2-way bank alias: free)
  int nn4 = tid & 15;        // n = nn4*4
#pragma unroll
  for (int it = 0; it < 4; it++) {
    int kk = (tid >> 4) + it * 16;
    float4 v = *(const float4*)(I + (size_t)(k0 + kk) * N + n0 + nn4 * 4);
    float* dst = ld + kk * 65 + nn4 * 4;
    dst[0] = v.x; dst[1] = v.y; dst[2] = v.z; dst[3] = v.w;
  }
  __syncthreads();
  // write: u16x4 along k (lanes 0-15 cover 128B of one out row; 2-way LDS alias)
  int kc = tid & 15;         // k = kc*4
#pragma unroll
  for (int it = 0; it < 4; it++) {
    int n = (tid >> 4) + it * 16;
    u16x4 w;
    w.x = f2bf(ld[(kc * 4 + 0) * 65 + n]);
    w.y = f2bf(ld[(kc * 4 + 1) * 65 + n]);
    w.z = f2bf(ld[(kc * 4 + 2) * 65 + n]);
    w.w = f2bf(ld[(kc * 4 + 3) * 65 + n]);
    *(u16x4*)(O + (size_t)(n0 + n) * K + k0 + kc * 4) = w;
  }
}

// ------- LayerNorm over bf16 input: x1b bf16 [rows][1024] -> h2 bf16 -------
__global__ __launch_bounds__(256) void ln_bf16_kernel(const u16* __restrict__ xb,
                                                      const float* __restrict__ g,
                                                      const float* __restrict__ beta,
                                                      u16* __restrict__ out) {
  int row = blockIdx.x;
  int tid = threadIdx.x;
  u16x4 vr = *(const u16x4*)(xb + (size_t)row * 1024 + tid * 4);
  float v0 = bf2f(vr.x), v1 = bf2f(vr.y), v2 = bf2f(vr.z), v3 = bf2f(vr.w);
  float s = v0 + v1 + v2 + v3;
  float ss = v0 * v0 + v1 * v1 + v2 * v2 + v3 * v3;
#pragma unroll
  for (int m = 1; m < 64; m <<= 1) { s += __shfl_xor(s, m); ss += __shfl_xor(ss, m); }
  __shared__ float red[8];
  int wave = tid >> 6, lane = tid & 63;
  if (lane == 0) { red[wave] = s; red[4 + wave] = ss; }
  __syncthreads();
  s = red[0] + red[1] + red[2] + red[3];
  ss = red[4] + red[5] + red[6] + red[7];
  float mean = s * (1.0f / 1024.0f);
  float var = ss * (1.0f / 1024.0f) - mean * mean;
  float rstd = rsqrtf(var + 1e-5f);
  float4 gv = ((const float4*)g)[tid];
  float4 bv = ((const float4*)beta)[tid];
  u16x4 o;
  o.x = f2bf((v0 - mean) * rstd * gv.x + bv.x);
  o.y = f2bf((v1 - mean) * rstd * gv.y + bv.y);
  o.z = f2bf((v2 - mean) * rstd * gv.z + bv.z);
  o.w = f2bf((v3 - mean) * rstd * gv.w + bv.w);
  *(u16x4*)(out + (size_t)row * 1024 + tid * 4) = o;
}

// ---------------- 256x256 8-phase GEMM: C[M][N] = A[M][K] * Bt[N][K]^T ----------------
// m201-conformant schedule (r13 proven). EP 0: QKV scatter (token-major);
// EP 2: relu+bias bf16 (FFN1).
template <int EP>
__global__ __launch_bounds__(512, 2) void gemm8p(const u16* __restrict__ A,
                                                 const u16* __restrict__ Bt,
                                                 int M, int N, int K, int KS,
                                                 void* __restrict__ out0,
                                                 u16* __restrict__ out1,
                                                 u16* __restrict__ out2,
                                                 const float* __restrict__ bias) {
  __shared__ __align__(16) u16 lds[65536];  // A at 0, B at 32768 (u16 units)
  const int tid = threadIdx.x;
  const int lane = tid & 63, wave = tid >> 6;
  const int lo = lane & 15, hi = lane >> 4;
  const int wm = wave >> 2, wn = wave & 3;
  // XCD swizzle
  int gx = gridDim.x;
  int lin = blockIdx.y * gx + blockIdx.x;
  int nwg = gx * gridDim.y;
  int cpx = nwg >> 3;
  int swz = (lin & 7) * cpx + (lin >> 3);
  int bm0 = (swz / gx) * 256, bn0 = (swz % gx) * 256;
  int kbeg = blockIdx.z * KS;
  int T = KS >> 6;

  int rs_ = tid >> 3, ss_ = (tid & 7) ^ (rs_ & 7);
  const u16* srcA = A + (size_t)(bm0 + rs_) * K + kbeg + ss_ * 8;
  const u16* srcB = Bt + (size_t)(bn0 + rs_) * K + kbeg + ss_ * 8;
  const size_t i1 = (size_t)64 * K;
  const size_t h1 = (size_t)128 * K;
  const int dst0 = wave * 512;
  const int dst1 = 4096 + wave * 512;

  const int rpA = wm * 16 + lo;
  const int rpB = wn * 16 + lo;
  const int sp0 = (hi ^ (lo & 7)) * 8;

  f32x4 acc[8][4] = {};
  bf16x8 a[4][2], b0[2][2], b1[2][2];

  auto stageA = [&](int buf, int h, int koff) {
    const u16* s = srcA + koff + (h ? h1 : 0);
    u16* d = lds + (buf * 2 + h) * 8192;
    gload_lds16(s, d + dst0);
    gload_lds16(s + i1, d + dst1);
  };
  auto stageB = [&](int buf, int h, int koff) {
    const u16* s = srcB + koff + (h ? h1 : 0);
    u16* d = lds + 32768 + (buf * 2 + h) * 8192;
    gload_lds16(s, d + dst0);
    gload_lds16(s + i1, d + dst1);
  };
  auto loadA = [&](int buf, int h) {
    const u16* base = lds + (buf * 2 + h) * 8192 + rpA * 64;
#pragma unroll
    for (int m = 0; m < 4; m++) {
      a[m][0] = *(const bf16x8*)(base + m * 2048 + sp0);
      a[m][1] = *(const bf16x8*)(base + m * 2048 + (sp0 ^ 32));
    }
  };
  auto loadB = [&](bf16x8 (&bb)[2][2], int buf, int g) {
    const u16* base = lds + 32768 + (buf * 2 + g) * 8192 + rpB * 64;
#pragma unroll
    for (int n = 0; n < 2; n++) {
      bb[n][0] = *(const bf16x8*)(base + n * 4096 + sp0);
      bb[n][1] = *(const bf16x8*)(base + n * 4096 + (sp0 ^ 32));
    }
  };
  auto mmac = [&](int mh, int np, bf16x8 (&bb)[2][2]) {
    __builtin_amdgcn_s_setprio(1);
#pragma unroll
    for (int m = 0; m < 4; m++)
#pragma unroll
      for (int n = 0; n < 2; n++) {
        acc[mh + m][np + n] = MFMA16(a[m][0], bb[n][0], acc[mh + m][np + n]);
        acc[mh + m][np + n] = MFMA16(a[m][1], bb[n][1], acc[mh + m][np + n]);
      }
    __builtin_amdgcn_s_setprio(0);
  };

  stageA(0, 0, 0); stageB(0, 0, 0); stageB(0, 1, 0); stageA(0, 1, 0);
  VMCNT(4);
  __builtin_amdgcn_s_barrier();

  for (int t = 0; t < T; ++t) {
    int cur = t & 1, nxt = cur ^ 1;
    bool more = (t + 1 < T);
    int koff = (t + 1) * 64;
    // P1
    loadA(cur, 0); loadB(b0, cur, 0);
    if (more) stageA(nxt, 0, koff);
    __builtin_amdgcn_s_barrier();
    LGKM0();
    __builtin_amdgcn_sched_barrier(0);
    mmac(0, 0, b0);
    __builtin_amdgcn_s_barrier();
    // P2
    loadB(b1, cur, 1);
    if (more) { stageB(nxt, 0, koff); VMCNT(6); } else { VMCNT(2); }
    __builtin_amdgcn_s_barrier();
    LGKM0();
    __builtin_amdgcn_sched_barrier(0);
    mmac(0, 2, b1);
    __builtin_amdgcn_s_barrier();
    // P3
    loadA(cur, 1);
    if (more) { stageB(nxt, 1, koff); VMCNT(6); } else { VMCNT(0); }
    __builtin_amdgcn_s_barrier();
    LGKM0();
    __builtin_amdgcn_sched_barrier(0);
    mmac(4, 0, b0);
    __builtin_amdgcn_s_barrier();
    // P4
    if (more) { stageA(nxt, 1, koff); VMCNT(4); }
    __builtin_amdgcn_s_barrier();
    mmac(4, 2, b1);
    __builtin_amdgcn_s_barrier();
  }

  const int sec = (EP == 0) ? (bn0 >> 10) : 0;
#pragma unroll
  for (int mt = 0; mt < 8; mt++) {
    int gr0 = bm0 + (mt >> 2) * 128 + (mt & 3) * 32 + wm * 16 + hi * 4;
#pragma unroll
    for (int nt = 0; nt < 4; nt++) {
      int gc = bn0 + (nt >> 1) * 128 + (nt & 1) * 64 + wn * 16 + lo;
      if constexpr (EP == 0) {
        int b_ = gr0 >> 11, t_ = gr0 & 2047;
        int nn = gc & 1023, h_ = nn >> 6, e_ = nn & 63;
        size_t bh = (size_t)(b_ * 16 + h_);
        if (sec == 2) {  // vT: 4 consecutive t per thread -> one 8B store
          u32x2 w;
          w.x = cvt_pk_bf16(acc[mt][nt][0], acc[mt][nt][1]);
          w.y = cvt_pk_bf16(acc[mt][nt][2], acc[mt][nt][3]);
          *(u32x2*)(out2 + (bh * 64 + e_) * 2048 + t_) = w;
        } else {
          float sc = (sec == 0) ? 0.0450842200f : 1.0f;  // q pre-scale D^-0.5*log2e
          u16* dst = (sec == 0) ? (u16*)out0 : out1;
#pragma unroll
          for (int j = 0; j < 4; j++)
            dst[(bh * 2048 + t_ + j) * 64 + e_] = f2bf(acc[mt][nt][j] * sc);
        }
      } else if constexpr (EP == 2) {
#pragma unroll
        for (int j = 0; j < 4; j++) {
          int gr = gr0 + j;
          float v = acc[mt][nt][j] + bias[gc];
          ((u16*)out0)[(size_t)gr * N + gc] = f2bf(fmaxf(v, 0.0f));
        }
      }
    }
  }
}

// ---- 128x128 8-wave 4-phase GEMM (BK=128), r13 proven schedule ----
// EPR 0 (Wo):   x1b(bf16) = acc + bias + resf(fp32)
// EPR 1 (FFN2): outf(fp32) = acc + bias + bf2f(resb)
template <int EPR>
__global__ __launch_bounds__(512, 2) void gemm128(const u16* __restrict__ A,
                                                  const u16* __restrict__ Bt,
                                                  int M, int N, int K,
                                                  const float* __restrict__ bias,
                                                  const float* __restrict__ resf,
                                                  const u16* __restrict__ resb,
                                                  float* __restrict__ outf,
                                                  u16* __restrict__ outb) {
  __shared__ __align__(16) u16 lds[65536];  // A at 0, B at 32768 (u16 units)
  const int tid = threadIdx.x;
  const int lane = tid & 63, wave = tid >> 6;
  const int lo = lane & 15, hi = lane >> 4;
  const int wm = wave >> 1, wn = wave & 1;
  // XCD swizzle
  int gx = gridDim.x;
  int lin = blockIdx.y * gx + blockIdx.x;
  int nwg = gx * gridDim.y;
  int cpx = nwg >> 3;
  int swz = (lin & 7) * cpx + (lin >> 3);
  int bm0 = (swz / gx) * 128, bn0 = (swz % gx) * 128;
  int T = K >> 7;  // BK = 128

  int rs_ = tid >> 4, ss_ = (tid & 15) ^ (rs_ & 15);
  const u16* srcA = A + (size_t)(bm0 + rs_) * K + ss_ * 8;
  const u16* srcB = Bt + (size_t)(bn0 + rs_) * K + ss_ * 8;
  const size_t i1 = (size_t)32 * K;   // chunk-set 1: +32 rows
  const size_t h1 = (size_t)64 * K;   // half 1: +64 rows
  const int dst0 = wave * 512;
  const int dst1 = 4096 + wave * 512;

  const int rA = wm * 16 + lo;        // local row within A-half
  const int cB = wn * 16 + lo;        // local col base within B-half

  f32x4 acc[2][4] = {};
  bf16x8 a[4], b0[2][4], b1[2][4];

  auto stageA = [&](int buf, int h, int koff) {
    const u16* s = srcA + koff + (h ? h1 : 0);
    u16* d = lds + (buf * 2 + h) * 8192;
    gload_lds16(s, d + dst0);
    gload_lds16(s + i1, d + dst1);
  };
  auto stageB = [&](int buf, int h, int koff) {
    const u16* s = srcB + koff + (h ? h1 : 0);
    u16* d = lds + 32768 + (buf * 2 + h) * 8192;
    gload_lds16(s, d + dst0);
    gload_lds16(s + i1, d + dst1);
  };
  auto loadA_ = [&](int buf, int h) {
    const u16* base = lds + (buf * 2 + h) * 8192 + rA * 128;
#pragma unroll
    for (int kk = 0; kk < 4; kk++)
      a[kk] = *(const bf16x8*)(base + (((kk * 4 + hi) ^ lo) << 3));
  };
  auto loadB_ = [&](bf16x8 (&bb)[2][4], int buf, int g) {
    const u16* base = lds + 32768 + (buf * 2 + g) * 8192 + cB * 128;
#pragma unroll
    for (int n = 0; n < 2; n++)
#pragma unroll
      for (int kk = 0; kk < 4; kk++)
        bb[n][kk] = *(const bf16x8*)(base + n * 4096 + (((kk * 4 + hi) ^ lo) << 3));
  };
  auto mmac = [&](int mt, int g, bf16x8 (&bb)[2][4]) {
    __builtin_amdgcn_s_setprio(1);
#pragma unroll
    for (int n = 0; n < 2; n++)
#pragma unroll
      for (int kk = 0; kk < 4; kk++)
        acc[mt][g * 2 + n] = MFMA16(a[kk], bb[n][kk], acc[mt][g * 2 + n]);
    __builtin_amdgcn_s_setprio(0);
  };

  // prologue: tile 0, order Ah0,Bh0,Bh1,Ah1; Ah0,Bh0 confirmed, Bh1,Ah1 in flight
  stageA(0, 0, 0); stageB(0, 0, 0); stageB(0, 1, 0); stageA(0, 1, 0);
  VMCNT(4);
  __builtin_amdgcn_s_barrier();

  for (int t = 0; t < T; ++t) {
    int cur = t & 1, nxt = cur ^ 1;
    bool more = (t + 1 < T);
    int koff = (t + 1) * 128;
    // P1: a = A-h0, b0 = B-h0; MFMA mt0 x nt{0,1}
    loadA_(cur, 0); loadB_(b0, cur, 0);
    if (more) stageA(nxt, 0, koff);
    __builtin_amdgcn_s_barrier();
    LGKM0();
    __builtin_amdgcn_sched_barrier(0);
    mmac(0, 0, b0);
    __builtin_amdgcn_s_barrier();
    // P2: b1 = B-h1; MFMA mt0 x nt{2,3}
    loadB_(b1, cur, 1);
    if (more) { stageB(nxt, 0, koff); VMCNT(6); } else { VMCNT(2); }
    __builtin_amdgcn_s_barrier();
    LGKM0();
    __builtin_amdgcn_sched_barrier(0);
    mmac(0, 1, b1);
    __builtin_amdgcn_s_barrier();
    // P3: a = A-h1; MFMA mt1 x nt{0,1} (reuse b0)
    loadA_(cur, 1);
    if (more) { stageB(nxt, 1, koff); VMCNT(6); } else { VMCNT(0); }
    __builtin_amdgcn_s_barrier();
    LGKM0();
    __builtin_amdgcn_sched_barrier(0);
    mmac(1, 0, b0);
    __builtin_amdgcn_s_barrier();
    // P4: MFMA mt1 x nt{2,3} (reuse b1)
    if (more) { stageA(nxt, 1, koff); VMCNT(4); }
    __builtin_amdgcn_s_barrier();
    mmac(1, 1, b1);
    __builtin_amdgcn_s_barrier();
  }

  // epilogue
#pragma unroll
  for (int mt = 0; mt < 2; mt++) {
    int gr0 = bm0 + mt * 64 + wm * 16 + hi * 4;
#pragma unroll
    for (int nt = 0; nt < 4; nt++) {
      int gc = bn0 + nt * 32 + wn * 16 + lo;
      float bb = bias[gc];
#pragma unroll
      for (int j = 0; j < 4; j++) {
        int gr = gr0 + j;
        if constexpr (EPR == 0) {
          outb[(size_t)gr * N + gc] =
              f2bf(acc[mt][nt][j] + bb + resf[(size_t)gr * N + gc]);
        } else {
          outf[(size_t)gr * N + gc] =
              acc[mt][nt][j] + bb + bf2f(resb[(size_t)gr * N + gc]);
        }
      }
    }
  }
}

// ------------------------- causal flash attention (paired Q-tiles) -------------------------
// r8 structure + T5 setprio. Grid transposed for XCD K/V locality: x=bh (32), y=pi (16);
// all 16 blocks of a bh land on XCD bh%8 -> per-bh K/V fetched into one L2 (confirmed
// r22: attn dropped out of top-5; total -2us).
__global__ __launch_bounds__(512, 4) void attn_kernel(const u16* __restrict__ q,
                                                      const u16* __restrict__ k,
                                                      const u16* __restrict__ vt,
                                                      u16* __restrict__ o) {
  __shared__ __align__(16) u16 Ks[2][64 * 64];
  __shared__ __align__(16) u16 Vs[2][64 * 64];
  __shared__ __align__(16) u16 Ps[8][16 * 72];
  int bh = blockIdx.x;                      // 0..31 (fast dim -> XCD = bh%8)
  int pi = blockIdx.y;                      // 0..15 (slow dim: pi=0 dispatches first)
  int tid = threadIdx.x, lane = tid & 63, wave = tid >> 6;
  int lo = lane & 15, hi = lane >> 4;
  int grp = wave >> 2;                      // 0: long tile, 1: short tile
  int qblk_w = grp ? pi : (31 - pi);
  int qb0 = qblk_w * 64;
  int nkb = 32 - pi;                        // loop length = long tile's KV count
  const u16* qbase = q + (size_t)bh * 2048 * 64;
  const u16* kbase = k + (size_t)bh * 2048 * 64;
  const u16* vbase = vt + (size_t)bh * 64 * 2048;

  int srow = tid >> 3;
  int ssl = (tid & 7) ^ (srow & 7);         // both-sides XOR swizzle
  int kOff = srow * 64 + ssl * 8;
  int vOff = srow * 2048 + ssl * 8;

  int qrow = qb0 + (wave & 3) * 16 + lo;
  bf16x8 qf0 = *(const bf16x8*)(qbase + (size_t)qrow * 64 + hi * 8);
  bf16x8 qf1 = *(const bf16x8*)(qbase + (size_t)qrow * 64 + 32 + hi * 8);

  float l_r = 0.0f;
  f32x4 of[4] = {};
  u16* Pw = Ps[wave];

  auto stage = [&](int b, int kb) {
    gload_lds16(kbase + (size_t)kb * 4096 + kOff, Ks[b] + wave * 512);
    gload_lds16(vbase + kb * 64 + vOff, Vs[b] + wave * 512);
  };

  stage(0, 0);
  __syncthreads();

  for (int kb = 0; kb < nkb; kb++) {
    int cur = kb & 1;
    if (kb + 1 < nkb) stage(cur ^ 1, kb + 1);
    if (kb <= qblk_w) {
      const u16* Kb = Ks[cur];
      const u16* Vb = Vs[cur];
      f32x4 s4[4] = {};
      __builtin_amdgcn_s_setprio(1);
#pragma unroll
      for (int nt = 0; nt < 4; nt++) {
        int r = nt * 16 + lo, rw = r & 7;
        bf16x8 kf0 = *(const bf16x8*)(Kb + r * 64 + ((hi ^ rw) << 3));
        bf16x8 kf1 = *(const bf16x8*)(Kb + r * 64 + (((hi + 4) ^ rw) << 3));
        s4[nt] = MFMA16(kf0, qf0, s4[nt]);
        s4[nt] = MFMA16(kf1, qf1, s4[nt]);
      }
      __builtin_amdgcn_s_setprio(0);
      float rs = 0.0f;
      bool diag = (kb == qblk_w);
#pragma unroll
      for (int nt = 0; nt < 4; nt++) {
        float e0, e1, e2, e3;
        if (diag) {
          int key = kb * 64 + nt * 16 + hi * 4;
          e0 = (key     > qrow) ? 0.0f : __builtin_amdgcn_exp2f(s4[nt][0]);
          e1 = (key + 1 > qrow) ? 0.0f : __builtin_amdgcn_exp2f(s4[nt][1]);
          e2 = (key + 2 > qrow) ? 0.0f : __builtin_amdgcn_exp2f(s4[nt][2]);
          e3 = (key + 3 > qrow) ? 0.0f : __builtin_amdgcn_exp2f(s4[nt][3]);
        } else {
          e0 = __builtin_amdgcn_exp2f(s4[nt][0]);
          e1 = __builtin_amdgcn_exp2f(s4[nt][1]);
          e2 = __builtin_amdgcn_exp2f(s4[nt][2]);
          e3 = __builtin_amdgcn_exp2f(s4[nt][3]);
        }
        rs += (e0 + e1) + (e2 + e3);
        u32x2 w;
        w.x = cvt_pk_bf16(e0, e1);
        w.y = cvt_pk_bf16(e2, e3);
        *(u32x2*)(Pw + lo * 72 + nt * 16 + hi * 4) = w;
      }
      rs += __shfl_xor(rs, 16);
      rs += __shfl_xor(rs, 32);
      l_r += rs;
      bf16x8 pb0 = *(const bf16x8*)(Pw + lo * 72 + hi * 8);
      bf16x8 pb1 = *(const bf16x8*)(Pw + lo * 72 + 32 + hi * 8);
      __builtin_amdgcn_s_setprio(1);
#pragma unroll
      for (int et = 0; et < 4; et++) {
        int e = et * 16 + lo, ew = e & 7;
        bf16x8 v0 = *(const bf16x8*)(Vb + e * 64 + ((hi ^ ew) << 3));
        bf16x8 v1 = *(const bf16x8*)(Vb + e * 64 + (((hi + 4) ^ ew) << 3));
        of[et] = MFMA16(v0, pb0, of[et]);
        of[et] = MFMA16(v1, pb1, of[et]);
      }
      __builtin_amdgcn_s_setprio(0);
    }
    __syncthreads();
  }
  int hh = bh & 15, bb = bh >> 4;
  float inv = 1.0f / l_r;
  size_t obase = ((size_t)(bb * 2048 + qrow)) * 1024 + hh * 64 + hi * 4;
#pragma unroll
  for (int et = 0; et < 4; et++) {
    u32x2 w;
    w.x = cvt_pk_bf16(of[et][0] * inv, of[et][1] * inv);
    w.y = cvt_pk_bf16(of[et][2] * inv, of[et][3] * inv);
    *(u32x2*)(o + obase + et * 16) = w;
  }
}

extern "C" void kernel_launch(void* const* d_in, const int* in_sizes, int n_in,
                              void* d_out, int out_size, void* d_ws, size_t ws_size,
                              hipStream_t stream) {
  const float* x = (const float*)d_in[0];
  const float* Wq = (const float*)d_in[1];
  const float* Wk = (const float*)d_in[2];
  const float* Wv = (const float*)d_in[3];
  const float* Wo = (const float*)d_in[4];
  const float* bo = (const float*)d_in[5];
  const float* W1 = (const float*)d_in[6];
  const float* b1 = (const float*)d_in[7];
  const float* W2 = (const float*)d_in[8];
  const float* b2 = (const float*)d_in[9];
  const float* g1 = (const float*)d_in[10];
  const float* be1 = (const float*)d_in[11];
  const float* g2 = (const float*)d_in[12];
  const float* be2 = (const float*)d_in[13];
  float* out = (float*)d_out;
  char* ws = (char*)d_ws;
  const size_t MB = 1024ull * 1024ull;

  // workspace map (72MB peak):
  //  0- 8 : h (ln1) -> o (attn out)          [o dead after Wo gemm]
  //  8-14 : BtQKV [dead after QKV gemm]  -> h2 (ln2 out, 8-16)
  // 14-16 : WoT   [dead after Wo gemm]
  // 16-24 : W1T   [dead after FFN1]
  // 24-32 : x1b (bf16 residual)          [Wo gemm .. FFN2]
  // 32-40 : qb    [dead after attn]      -> yb (32-64, FFN1 out)
  // 40-48 : kb
  // 48-56 : vtb
  // 64-72 : W2T   [dead after FFN2]
  u16* h = (u16*)(ws + 0);
  u16* o = h;
  u16* BtQKV = (u16*)(ws + 8 * MB);
  u16* WoT = (u16*)(ws + 14 * MB);
  u16* W1T = (u16*)(ws + 16 * MB);
  u16* x1b = (u16*)(ws + 24 * MB);
  u16* W2T = (u16*)(ws + 64 * MB);
  u16* qb = (u16*)(ws + 32 * MB);
  u16* kb = (u16*)(ws + 40 * MB);
  u16* vtb = (u16*)(ws + 48 * MB);
  u16* h2 = (u16*)(ws + 8 * MB);
  u16* yb = (u16*)(ws + 32 * MB);

  // 1. prep: LN1 + all weight transposes (one launch, vectorized)
  prep_kernel<<<7168, 256, 0, stream>>>(x, g1, be1, h, Wq, Wk, Wv, BtQKV,
                                        Wo, WoT, W1, W1T, W2, W2T);
  // 2. QKV projection: [4096][1024] x [3072][1024]^T, scatter epilogue (q pre-scaled)
  gemm8p<0><<<dim3(12, 16), 512, 0, stream>>>(h, BtQKV, 4096, 3072, 1024, 1024,
                                              (void*)qb, kb, vtb, nullptr);
  // 3. causal attention -> o; grid (bh=32, pi=16): per-bh K/V pinned to one XCD
  attn_kernel<<<dim3(32, 16), 512, 0, stream>>>(qb, kb, vtb, o);
  // 4. Wo: x1b (bf16) = x + o@Wo + bo, 128^2 8-wave tiles
  gemm128<0><<<dim3(8, 32), 512, 0, stream>>>(o, WoT, 4096, 1024, 1024, bo,
                                              x, nullptr, nullptr, x1b);
  // 5. LN2: x1b (bf16) -> h2 (bf16)
  ln_bf16_kernel<<<4096, 256, 0, stream>>>(x1b, g2, be2, h2);
  // 6. FFN1: y = relu(h2@W1 + b1) (bf16), 256^2 tiles
  gemm8p<2><<<dim3(16, 16), 512, 0, stream>>>(h2, W1T, 4096, 4096, 1024, 1024,
                                              (void*)yb, nullptr, nullptr, b1);
  // 7. FFN2: out (fp32) = x1b + y@W2 + b2, 128^2 8-wave tiles, K=4096
  gemm128<1><<<dim3(8, 32), 512, 0, stream>>>(yb, W2T, 4096, 1024, 4096, b2,
                                              nullptr, x1b, out, nullptr);
}